// Round 12
// baseline (153.703 us; speedup 1.0000x reference)
//
#include <hip/hip_runtime.h>
#include <hip/hip_bf16.h>
#include <stdint.h>

typedef short short8 __attribute__((ext_vector_type(8)));
typedef short short4v __attribute__((ext_vector_type(4)));
typedef float f32x4 __attribute__((ext_vector_type(4)));

__device__ __forceinline__ void gload16(const void* g, void* l) {
  __builtin_amdgcn_global_load_lds((const __attribute__((address_space(1))) void*)g,
                                   (__attribute__((address_space(3))) void*)l, 16, 0, 0);
}

__device__ __forceinline__ unsigned short f2b(float f) {
  unsigned int x = __float_as_uint(f);
  x += 0x7fffu + ((x >> 16) & 1u);
  return (unsigned short)(x >> 16);
}

// ==================== prep ====================
// [0,8192) cvt x->xb | [8192,9216) Wv->Wt2_V^T | [9216,9472) M^T=Wk.Wq^T | [9472,9504) sums=0
__global__ __launch_bounds__(256) void prep(
    const float* __restrict__ x, const float* __restrict__ Wq,
    const float* __restrict__ Wk, const float* __restrict__ Wv,
    unsigned short* __restrict__ xb, unsigned short* __restrict__ Wt2,
    float* __restrict__ sums)
{
  __shared__ __align__(16) char smem[16384];
  const int bid = blockIdx.x;
  const int tid = threadIdx.x;
  if (bid < 8192) {
    const int i = bid * 256 + tid;
    const float4 f = ((const float4*)x)[i];
    union { unsigned short u[4]; uint2 v; } o;
    o.u[0] = f2b(f.x); o.u[1] = f2b(f.y); o.u[2] = f2b(f.z); o.u[3] = f2b(f.w);
    ((uint2*)xb)[i] = o.v;
  } else if (bid < 9216) {
    float (*tb)[33] = (float(*)[33])smem;
    const int t = bid - 8192;
    const int bx = t & 31, by = t >> 5;
    const int tx = tid & 31, ty = tid >> 5;
    const int xcol = bx * 32 + tx, y0 = by * 32;
    #pragma unroll
    for (int i = 0; i < 4; ++i)
      tb[ty + i * 8][tx] = Wv[(long long)(y0 + ty + i * 8) * 1024 + xcol];
    __syncthreads();
    unsigned short* O = Wt2 + 1024 * 1024;
    const int xo = by * 32 + tx, yo0 = bx * 32;
    #pragma unroll
    for (int i = 0; i < 4; ++i)
      O[(long long)(yo0 + ty + i * 8) * 1024 + xo] = f2b(tb[tx][ty + i * 8]);
  } else if (bid < 9472) {
    const int t = bid - 9216;
    const int bx = t & 15, by = t >> 4;
    const int row0 = by * 64, col0 = bx * 64;
    const int wave = tid >> 6, lane = tid & 63;
    const int wr = wave >> 1, wc = wave & 1;
    const int l15 = lane & 15, lk = lane >> 4;
    const int sr = lane >> 3, sg = lane & 7;
    char* lA = smem;
    char* lB = smem + 8192;
    const int rA = wr * 32 + l15, cB = wc * 32 + l15;
    const int xorA = (rA & 7) << 4, xorB = (cB & 7) << 4;
    const int kb = lk * 16;
    f32x4 acc[2][2];
    #pragma unroll
    for (int m = 0; m < 2; ++m)
      #pragma unroll
      for (int n = 0; n < 2; ++n) acc[m][n] = (f32x4)0.0f;
    for (int kt = 0; kt < 16; ++kt) {
      const int kc = kt * 64;
      short8 va[2], vb[2];
      int rr[2];
      #pragma unroll
      for (int j = 0; j < 2; ++j) {
        const int ci = wave * 2 + j;
        const int r = ci * 8 + sr;
        rr[j] = r;
        const float* pa = Wk + (long long)(row0 + r) * 1024 + kc + sg * 8;
        const float* pb = Wq + (long long)(col0 + r) * 1024 + kc + sg * 8;
        const float4 a0 = *(const float4*)pa, a1 = *(const float4*)(pa + 4);
        const float4 b0 = *(const float4*)pb, b1 = *(const float4*)(pb + 4);
        va[j][0] = (short)f2b(a0.x); va[j][1] = (short)f2b(a0.y);
        va[j][2] = (short)f2b(a0.z); va[j][3] = (short)f2b(a0.w);
        va[j][4] = (short)f2b(a1.x); va[j][5] = (short)f2b(a1.y);
        va[j][6] = (short)f2b(a1.z); va[j][7] = (short)f2b(a1.w);
        vb[j][0] = (short)f2b(b0.x); vb[j][1] = (short)f2b(b0.y);
        vb[j][2] = (short)f2b(b0.z); vb[j][3] = (short)f2b(b0.w);
        vb[j][4] = (short)f2b(b1.x); vb[j][5] = (short)f2b(b1.y);
        vb[j][6] = (short)f2b(b1.z); vb[j][7] = (short)f2b(b1.w);
      }
      __syncthreads();
      #pragma unroll
      for (int j = 0; j < 2; ++j) {
        const int off = rr[j] * 128 + ((sg * 16) ^ ((rr[j] & 7) << 4));
        *(short8*)(lA + off) = va[j];
        *(short8*)(lB + off) = vb[j];
      }
      __syncthreads();
      #pragma unroll
      for (int ks = 0; ks < 2; ++ks) {
        short8 af[2], bf[2];
        #pragma unroll
        for (int m = 0; m < 2; ++m)
          af[m] = *(const short8*)(lA + (rA + m * 16) * 128 + ((ks * 64 + kb) ^ xorA));
        #pragma unroll
        for (int n = 0; n < 2; ++n)
          bf[n] = *(const short8*)(lB + (cB + n * 16) * 128 + ((ks * 64 + kb) ^ xorB));
        #pragma unroll
        for (int m = 0; m < 2; ++m)
          #pragma unroll
          for (int n = 0; n < 2; ++n)
            acc[m][n] = __builtin_amdgcn_mfma_f32_16x16x32_bf16(af[m], bf[n], acc[m][n], 0, 0, 0);
      }
    }
    const int orow = row0 + wr * 32 + lk * 4;
    const int ocol = col0 + wc * 32 + l15;
    #pragma unroll
    for (int m = 0; m < 2; ++m)
      #pragma unroll
      for (int r = 0; r < 4; ++r)
        #pragma unroll
        for (int n = 0; n < 2; ++n)
          Wt2[(long long)(orow + m * 16 + r) * 1024 + ocol + n * 16] = f2b(acc[m][n][r]);
  } else {
    const int i = (bid - 9472) * 256 + tid;
    sums[i] = 0.f;
  }
}

// ==================== 256x256 8-phase GEMM machinery ====================
#define STG(buf, isB, half, kt) do {                                           \
    const unsigned short* _s = (isB) ? Bz : Az;                                \
    const int _ld = (isB) ? ldb : lda;                                         \
    const int _b0 = (isB) ? col0 : row0;                                       \
    char* _d = lds + (buf) * 65536 + (isB) * 32768 + (half) * 16384;           \
    _Pragma("unroll")                                                          \
    for (int _i = 0; _i < 2; ++_i) {                                           \
      const int _c = wave * 2 + _i;                                            \
      const int _row = (half) * 128 + _c * 8 + srow;                           \
      gload16(_s + (long long)(_b0 + _row) * _ld + (kt) * 64 + sgrp * 8,       \
              _d + _c * 1024);                                                 \
    } } while (0)

#define LDA8(dst, buf, mh) do {                                                \
    _Pragma("unroll")                                                          \
    for (int _m = 0; _m < 4; ++_m) {                                           \
      const int _r = wr * 128 + ((mh) * 4 + _m) * 16 + (lane & 15);            \
      const char* _p = lds + (buf) * 65536 + _r * 128;                         \
      const int _x = (_r & 7) << 4;                                            \
      dst[_m][0] = *(const short8*)(_p + ((kbyte) ^ _x));                      \
      dst[_m][1] = *(const short8*)(_p + ((64 + kbyte) ^ _x));                 \
    } } while (0)

#define LDB4(dst, buf, nh) do {                                                \
    _Pragma("unroll")                                                          \
    for (int _n = 0; _n < 2; ++_n) {                                           \
      const int _r = wc * 64 + ((nh) * 2 + _n) * 16 + (lane & 15);             \
      const char* _p = lds + (buf) * 65536 + 32768 + _r * 128;                 \
      const int _x = (_r & 7) << 4;                                            \
      dst[_n][0] = *(const short8*)(_p + ((kbyte) ^ _x));                      \
      dst[_n][1] = *(const short8*)(_p + ((64 + kbyte) ^ _x));                 \
    } } while (0)

#define MFMA16(mh, nh, av, bv) do {                                            \
    __builtin_amdgcn_s_setprio(1);                                             \
    _Pragma("unroll") for (int _n = 0; _n < 2; ++_n)                           \
    _Pragma("unroll") for (int _m = 0; _m < 4; ++_m)                           \
    _Pragma("unroll") for (int _k = 0; _k < 2; ++_k)                           \
      acc[(mh)*4+_m][(nh)*2+_n] = __builtin_amdgcn_mfma_f32_16x16x32_bf16(     \
          av[_m][_k], bv[_n][_k], acc[(mh)*4+_m][(nh)*2+_n], 0, 0, 0);         \
    __builtin_amdgcn_s_setprio(0);                                             \
  } while (0)

#define BAR() __builtin_amdgcn_s_barrier()
#define VM4() asm volatile("s_waitcnt vmcnt(4)" ::: "memory")
#define VM0() asm volatile("s_waitcnt vmcnt(0)" ::: "memory")

#define GEMM8_BODY(NT)                                                         \
  f32x4 acc[8][4];                                                             \
  _Pragma("unroll")                                                            \
  for (int m = 0; m < 8; ++m)                                                  \
    _Pragma("unroll")                                                          \
    for (int n = 0; n < 4; ++n) acc[m][n] = (f32x4)0.0f;                       \
  short8 a[4][2], b0[2][2], b1[2][2];                                          \
  STG(0, 1, 0, 0); STG(0, 1, 1, 0); STG(0, 0, 0, 0); STG(0, 0, 1, 0);          \
  STG(1, 1, 0, 1); STG(1, 1, 1, 1);                                            \
  VM4(); BAR();                                                                \
  for (int t = 0; t < (NT); ++t) {                                             \
    const bool pf = (t < (NT) - 1);                                            \
    LDA8(a, 0, 0); LDB4(b0, 0, 0);                                             \
    STG(1, 0, 0, 2 * t + 1);                                                   \
    BAR(); MFMA16(0, 0, a, b0); BAR();                                         \
    LDB4(b1, 0, 1);                                                            \
    STG(1, 0, 1, 2 * t + 1);                                                   \
    BAR(); MFMA16(0, 1, a, b1); BAR();                                         \
    LDA8(a, 0, 1);                                                             \
    if (pf) STG(0, 1, 0, 2 * t + 2);                                           \
    BAR(); MFMA16(1, 1, a, b1); BAR();                                         \
    if (pf) STG(0, 1, 1, 2 * t + 2);                                           \
    BAR(); MFMA16(1, 0, a, b0);                                                \
    if (pf) VM4(); else VM0();                                                 \
    BAR();                                                                     \
    LDA8(a, 1, 0); LDB4(b0, 1, 0);                                             \
    if (pf) STG(0, 0, 0, 2 * t + 2);                                           \
    BAR(); MFMA16(0, 0, a, b0); BAR();                                         \
    LDB4(b1, 1, 1);                                                            \
    if (pf) STG(0, 0, 1, 2 * t + 2);                                           \
    BAR(); MFMA16(0, 1, a, b1); BAR();                                         \
    LDA8(a, 1, 1);                                                             \
    if (pf) STG(1, 1, 0, 2 * t + 3);                                           \
    BAR(); MFMA16(1, 1, a, b1); BAR();                                         \
    if (pf) STG(1, 1, 1, 2 * t + 3);                                           \
    BAR(); MFMA16(1, 0, a, b0);                                                \
    if (pf) VM4();                                                             \
    BAR();                                                                     \
  }

// ---- [y|V] = x . [M^T ; Wv^T]^T ; grid (x=row 32, y=col 8) for XCD grouping ----
__global__ __launch_bounds__(512, 2) void gemm8_yv(
    const unsigned short* __restrict__ A, const unsigned short* __restrict__ Bt,
    unsigned short* __restrict__ y, unsigned short* __restrict__ vt)
{
  const int row0 = blockIdx.x * 256;
  const int col0 = blockIdx.y * 256;
  const unsigned short* Az = A;
  const unsigned short* Bz = Bt;
  const int lda = 1024, ldb = 1024;

  __shared__ __align__(16) char lds[131072];

  const int tid = threadIdx.x;
  const int wave = tid >> 6, lane = tid & 63;
  const int wr = wave >> 2, wc = wave & 3;
  const int srow = lane >> 3, sgrp = (lane & 7) ^ srow;
  const int kbyte = (lane >> 4) * 16;

  GEMM8_BODY(8)

  const int orow = row0 + wr * 128 + ((lane >> 4) << 2);
  const int ocol = col0 + wc * 64 + (lane & 15);
  if (col0 < 1024) {
    #pragma unroll
    for (int m = 0; m < 8; ++m)
      #pragma unroll
      for (int r = 0; r < 4; ++r) {
        const int rg = orow + m * 16 + r;
        #pragma unroll
        for (int n = 0; n < 4; ++n)
          y[(long long)rg * 1024 + ocol + n * 16] = f2b(acc[m][n][r]);
      }
  } else {
    const int b = row0 >> 11;
    const int t0 = (row0 & 2047) + wr * 128 + ((lane >> 4) << 2);
    const int d0 = (col0 - 1024) + wc * 64 + (lane & 15);
    #pragma unroll
    for (int n = 0; n < 4; ++n) {
      unsigned short* vrow = vt + ((long long)b * 1024 + d0 + n * 16) * 2048 + t0;
      #pragma unroll
      for (int m = 0; m < 8; ++m) {
        short4v v;
        v[0] = (short)f2b(acc[m][n][0]);
        v[1] = (short)f2b(acc[m][n][1]);
        v[2] = (short)f2b(acc[m][n][2]);
        v[3] = (short)f2b(acc[m][n][3]);
        *(short4v*)(vrow + m * 16) = v;
      }
    }
  }
}

// ---- P = exp((y x^T)/32) causal + rowsum atomics ----
__global__ __launch_bounds__(512, 2) void gemm8_p(
    const unsigned short* __restrict__ A, const unsigned short* __restrict__ Bt,
    unsigned short* __restrict__ outp, float* __restrict__ sums)
{
  const int z = blockIdx.z;
  const int row0 = blockIdx.y * 256;
  const int col0 = blockIdx.x * 256;
  if (col0 > row0 + 255) return;

  const unsigned short* Az = A + (long long)z * (2048 * 1024);
  const unsigned short* Bz = Bt + (long long)z * (2048 * 1024);
  const int lda = 1024, ldb = 1024;

  __shared__ __align__(16) char lds[131072];

  const int tid = threadIdx.x;
  const int wave = tid >> 6, lane = tid & 63;
  const int wr = wave >> 2, wc = wave & 3;
  const int srow = lane >> 3, sgrp = (lane & 7) ^ srow;
  const int kbyte = (lane >> 4) * 16;

  GEMM8_BODY(8)

  const int orow = row0 + wr * 128 + ((lane >> 4) << 2);
  const int ocol = col0 + wc * 64 + (lane & 15);
  unsigned short* out = outp + (long long)z * (2048 * 2048);
  #pragma unroll
  for (int m = 0; m < 8; ++m)
    #pragma unroll
    for (int r = 0; r < 4; ++r) {
      const int rg = orow + m * 16 + r;
      float rs = 0.f;
      #pragma unroll
      for (int n = 0; n < 4; ++n) {
        const int cg = ocol + n * 16;
        float p = (cg > rg) ? 0.0f : __expf(acc[m][n][r] * 0.03125f);
        rs += p;
        out[(long long)rg * 2048 + cg] = f2b(p);
      }
      #pragma unroll
      for (int off = 1; off < 16; off <<= 1) rs += __shfl_xor(rs, off);
      if ((lane & 15) == 0) atomicAdd(&sums[(long long)z * 2048 + rg], rs);
    }
}

// ==================== 128x64 2-phase PV (causal K-bound, XCD-grouped) ====================
// grid (x=stripe-sel 16, y=col 16, z=batch). id%8 = x%8 -> all 16 col-blocks of a
// stripe share one XCD (L2 reuse of the P stripe). Stripe pairing balances work.
// 4 blocks/CU (vs 2 at 128x128) to hide 2-phase latency.
__global__ __launch_bounds__(256) void gemm_pv(
    const unsigned short* __restrict__ P, const unsigned short* __restrict__ Vt,
    float* __restrict__ out, const float* __restrict__ sums)
{
  const int z = blockIdx.z;
  const int sx = blockIdx.x;
  const int by = (sx < 8) ? (15 - sx) : (sx - 8);
  const int row0 = by * 128;
  const int col0 = blockIdx.y * 64;

  const unsigned short* Az = P + (long long)z * (2048 * 2048);
  const unsigned short* Bz = Vt + (long long)z * (1024 * 2048);

  __shared__ __align__(16) char lds[24576];   // A [128][64] 16KB, B [64][64] 8KB

  const int tid = threadIdx.x;
  const int wave = tid >> 6;
  const int lane = tid & 63;
  const int wr = wave >> 1, wc = wave & 1;
  const int l15 = lane & 15, lk = lane >> 4;

  const int srow = lane >> 3;
  const int sgrp = (lane & 7) ^ srow;

  const int rA = wr * 64 + l15;
  const int cB = wc * 32 + l15;
  const int kb = lk * 16;
  const int xorA = (rA & 7) << 4;
  const int xorB = (cB & 7) << 4;

  f32x4 acc[4][2];
  #pragma unroll
  for (int m = 0; m < 4; ++m) { acc[m][0] = (f32x4)0.0f; acc[m][1] = (f32x4)0.0f; }

  const int nkt = (row0 + 128) >> 6;

  for (int kt = 0; kt < nkt; ++kt) {
    const int kc = kt * 64;
    #pragma unroll
    for (int i = 0; i < 4; ++i) {
      const int ci = wave * 4 + i;
      gload16(Az + (long long)(row0 + ci * 8 + srow) * 2048 + kc + sgrp * 8,
              lds + ci * 1024);
    }
    #pragma unroll
    for (int i = 0; i < 2; ++i) {
      const int ci = wave * 2 + i;
      gload16(Bz + (long long)(col0 + ci * 8 + srow) * 2048 + kc + sgrp * 8,
              lds + 16384 + ci * 1024);
    }
    __syncthreads();
    #pragma unroll
    for (int ks = 0; ks < 2; ++ks) {
      short8 af[4], bfr[2];
      #pragma unroll
      for (int m = 0; m < 4; ++m)
        af[m] = *(const short8*)(lds + (rA + m * 16) * 128 + ((ks * 64 + kb) ^ xorA));
      #pragma unroll
      for (int n = 0; n < 2; ++n)
        bfr[n] = *(const short8*)(lds + 16384 + (cB + n * 16) * 128 + ((ks * 64 + kb) ^ xorB));
      #pragma unroll
      for (int m = 0; m < 4; ++m)
        #pragma unroll
        for (int n = 0; n < 2; ++n)
          acc[m][n] = __builtin_amdgcn_mfma_f32_16x16x32_bf16(af[m], bfr[n], acc[m][n], 0, 0, 0);
    }
    __syncthreads();
  }

  const int orow = row0 + wr * 64 + lk * 4;
  const int ocol = col0 + wc * 32 + l15;
  const float* sz = sums + (long long)z * 2048;
  float* oz = out + (long long)z * (2048 * 1024);
  #pragma unroll
  for (int m = 0; m < 4; ++m)
    #pragma unroll
    for (int r = 0; r < 4; ++r) {
      const int rg = orow + m * 16 + r;
      const float iv = 1.0f / sz[rg];
      #pragma unroll
      for (int n = 0; n < 2; ++n)
        oz[(long long)rg * 1024 + ocol + n * 16] = acc[m][n][r] * iv;
    }
}

extern "C" void kernel_launch(void* const* d_in, const int* in_sizes, int n_in,
                              void* d_out, int out_size, void* d_ws, size_t ws_size,
                              hipStream_t stream) {
  (void)in_sizes; (void)n_in; (void)out_size; (void)ws_size;
  const float* x  = (const float*)d_in[0];
  const float* Wq = (const float*)d_in[1];
  const float* Wk = (const float*)d_in[2];
  const float* Wv = (const float*)d_in[3];
  float* out = (float*)d_out;

  char* ws = (char*)d_ws;
  unsigned short* xb  = (unsigned short*)(ws);               // 8192x1024 bf16
  unsigned short* Wt2 = (unsigned short*)(ws + 16777216);    // [2048][1024]: M^T ; Wv^T
  unsigned short* y   = (unsigned short*)(ws + 20971520);    // 8192x1024 bf16
  unsigned short* Vt  = (unsigned short*)(ws + 37748736);    // 4x1024x2048 bf16
  unsigned short* P   = (unsigned short*)(ws + 54525952);    // 4x2048x2048 bf16
  float*          sums = (float*)(ws + 88080384);            // 4x2048 fp32

  // 1. prep: cvt x, transpose Wv, M^T = Wk.Wq^T, zero sums
  prep<<<9504, 256, 0, stream>>>(x, Wq, Wk, Wv, xb, Wt2, sums);

  // 2. [y | V] = x . [M^T ; Wv^T]^T  (256 gemm8 blocks, XCD-grouped rows)
  gemm8_yv<<<dim3(32, 8), 512, 0, stream>>>(xb, Wt2, y, Vt);

  // 3. P = exp((y x^T)/32) causal, unnormalized bf16 + rowsums
  gemm8_p<<<dim3(8, 8, 4), 512, 0, stream>>>(y, xb, P, sums);

  // 4. context = (P Vt^T)/rowsum  (128x64 2-phase, 1024 blocks = 4/CU, XCD-grouped)
  gemm_pv<<<dim3(16, 16, 4), 256, 0, stream>>>(P, Vt, out, sums);
}

// Round 13
// 148.426 us; speedup vs baseline: 1.0356x; 1.0356x over previous
//
#include <hip/hip_runtime.h>
#include <hip/hip_bf16.h>
#include <stdint.h>

typedef short short8 __attribute__((ext_vector_type(8)));
typedef short short4v __attribute__((ext_vector_type(4)));
typedef float f32x4 __attribute__((ext_vector_type(4)));

__device__ __forceinline__ void gload16(const void* g, void* l) {
  __builtin_amdgcn_global_load_lds((const __attribute__((address_space(1))) void*)g,
                                   (__attribute__((address_space(3))) void*)l, 16, 0, 0);
}

__device__ __forceinline__ unsigned short f2b(float f) {
  unsigned int x = __float_as_uint(f);
  x += 0x7fffu + ((x >> 16) & 1u);
  return (unsigned short)(x >> 16);
}

// ==================== prep ====================
// [0,8192) cvt x->xb | [8192,9216) Wv->Wt2_V^T | [9216,9472) M^T=Wk.Wq^T | [9472,9504) sums=0
__global__ __launch_bounds__(256) void prep(
    const float* __restrict__ x, const float* __restrict__ Wq,
    const float* __restrict__ Wk, const float* __restrict__ Wv,
    unsigned short* __restrict__ xb, unsigned short* __restrict__ Wt2,
    float* __restrict__ sums)
{
  __shared__ __align__(16) char smem[16384];
  const int bid = blockIdx.x;
  const int tid = threadIdx.x;
  if (bid < 8192) {
    const int i = bid * 256 + tid;
    const float4 f = ((const float4*)x)[i];
    union { unsigned short u[4]; uint2 v; } o;
    o.u[0] = f2b(f.x); o.u[1] = f2b(f.y); o.u[2] = f2b(f.z); o.u[3] = f2b(f.w);
    ((uint2*)xb)[i] = o.v;
  } else if (bid < 9216) {
    float (*tb)[33] = (float(*)[33])smem;
    const int t = bid - 8192;
    const int bx = t & 31, by = t >> 5;
    const int tx = tid & 31, ty = tid >> 5;
    const int xcol = bx * 32 + tx, y0 = by * 32;
    #pragma unroll
    for (int i = 0; i < 4; ++i)
      tb[ty + i * 8][tx] = Wv[(long long)(y0 + ty + i * 8) * 1024 + xcol];
    __syncthreads();
    unsigned short* O = Wt2 + 1024 * 1024;
    const int xo = by * 32 + tx, yo0 = bx * 32;
    #pragma unroll
    for (int i = 0; i < 4; ++i)
      O[(long long)(yo0 + ty + i * 8) * 1024 + xo] = f2b(tb[tx][ty + i * 8]);
  } else if (bid < 9472) {
    const int t = bid - 9216;
    const int bx = t & 15, by = t >> 4;
    const int row0 = by * 64, col0 = bx * 64;
    const int wave = tid >> 6, lane = tid & 63;
    const int wr = wave >> 1, wc = wave & 1;
    const int l15 = lane & 15, lk = lane >> 4;
    const int sr = lane >> 3, sg = lane & 7;
    char* lA = smem;
    char* lB = smem + 8192;
    const int rA = wr * 32 + l15, cB = wc * 32 + l15;
    const int xorA = (rA & 7) << 4, xorB = (cB & 7) << 4;
    const int kb = lk * 16;
    f32x4 acc[2][2];
    #pragma unroll
    for (int m = 0; m < 2; ++m)
      #pragma unroll
      for (int n = 0; n < 2; ++n) acc[m][n] = (f32x4)0.0f;
    for (int kt = 0; kt < 16; ++kt) {
      const int kc = kt * 64;
      short8 va[2], vb[2];
      int rr[2];
      #pragma unroll
      for (int j = 0; j < 2; ++j) {
        const int ci = wave * 2 + j;
        const int r = ci * 8 + sr;
        rr[j] = r;
        const float* pa = Wk + (long long)(row0 + r) * 1024 + kc + sg * 8;
        const float* pb = Wq + (long long)(col0 + r) * 1024 + kc + sg * 8;
        const float4 a0 = *(const float4*)pa, a1 = *(const float4*)(pa + 4);
        const float4 b0 = *(const float4*)pb, b1 = *(const float4*)(pb + 4);
        va[j][0] = (short)f2b(a0.x); va[j][1] = (short)f2b(a0.y);
        va[j][2] = (short)f2b(a0.z); va[j][3] = (short)f2b(a0.w);
        va[j][4] = (short)f2b(a1.x); va[j][5] = (short)f2b(a1.y);
        va[j][6] = (short)f2b(a1.z); va[j][7] = (short)f2b(a1.w);
        vb[j][0] = (short)f2b(b0.x); vb[j][1] = (short)f2b(b0.y);
        vb[j][2] = (short)f2b(b0.z); vb[j][3] = (short)f2b(b0.w);
        vb[j][4] = (short)f2b(b1.x); vb[j][5] = (short)f2b(b1.y);
        vb[j][6] = (short)f2b(b1.z); vb[j][7] = (short)f2b(b1.w);
      }
      __syncthreads();
      #pragma unroll
      for (int j = 0; j < 2; ++j) {
        const int off = rr[j] * 128 + ((sg * 16) ^ ((rr[j] & 7) << 4));
        *(short8*)(lA + off) = va[j];
        *(short8*)(lB + off) = vb[j];
      }
      __syncthreads();
      #pragma unroll
      for (int ks = 0; ks < 2; ++ks) {
        short8 af[2], bf[2];
        #pragma unroll
        for (int m = 0; m < 2; ++m)
          af[m] = *(const short8*)(lA + (rA + m * 16) * 128 + ((ks * 64 + kb) ^ xorA));
        #pragma unroll
        for (int n = 0; n < 2; ++n)
          bf[n] = *(const short8*)(lB + (cB + n * 16) * 128 + ((ks * 64 + kb) ^ xorB));
        #pragma unroll
        for (int m = 0; m < 2; ++m)
          #pragma unroll
          for (int n = 0; n < 2; ++n)
            acc[m][n] = __builtin_amdgcn_mfma_f32_16x16x32_bf16(af[m], bf[n], acc[m][n], 0, 0, 0);
      }
    }
    const int orow = row0 + wr * 32 + lk * 4;
    const int ocol = col0 + wc * 32 + l15;
    #pragma unroll
    for (int m = 0; m < 2; ++m)
      #pragma unroll
      for (int r = 0; r < 4; ++r)
        #pragma unroll
        for (int n = 0; n < 2; ++n)
          Wt2[(long long)(orow + m * 16 + r) * 1024 + ocol + n * 16] = f2b(acc[m][n][r]);
  } else {
    const int i = (bid - 9472) * 256 + tid;
    sums[i] = 0.f;
  }
}

// ==================== 256x256 8-phase GEMM machinery ====================
#define STG(buf, isB, half, kt) do {                                           \
    const unsigned short* _s = (isB) ? Bz : Az;                                \
    const int _ld = (isB) ? ldb : lda;                                         \
    const int _b0 = (isB) ? col0 : row0;                                       \
    char* _d = lds + (buf) * 65536 + (isB) * 32768 + (half) * 16384;           \
    _Pragma("unroll")                                                          \
    for (int _i = 0; _i < 2; ++_i) {                                           \
      const int _c = wave * 2 + _i;                                            \
      const int _row = (half) * 128 + _c * 8 + srow;                           \
      gload16(_s + (long long)(_b0 + _row) * _ld + (kt) * 64 + sgrp * 8,       \
              _d + _c * 1024);                                                 \
    } } while (0)

#define LDA8(dst, buf, mh) do {                                                \
    _Pragma("unroll")                                                          \
    for (int _m = 0; _m < 4; ++_m) {                                           \
      const int _r = wr * 128 + ((mh) * 4 + _m) * 16 + (lane & 15);            \
      const char* _p = lds + (buf) * 65536 + _r * 128;                         \
      const int _x = (_r & 7) << 4;                                            \
      dst[_m][0] = *(const short8*)(_p + ((kbyte) ^ _x));                      \
      dst[_m][1] = *(const short8*)(_p + ((64 + kbyte) ^ _x));                 \
    } } while (0)

#define LDB4(dst, buf, nh) do {                                                \
    _Pragma("unroll")                                                          \
    for (int _n = 0; _n < 2; ++_n) {                                           \
      const int _r = wc * 64 + ((nh) * 2 + _n) * 16 + (lane & 15);             \
      const char* _p = lds + (buf) * 65536 + 32768 + _r * 128;                 \
      const int _x = (_r & 7) << 4;                                            \
      dst[_n][0] = *(const short8*)(_p + ((kbyte) ^ _x));                      \
      dst[_n][1] = *(const short8*)(_p + ((64 + kbyte) ^ _x));                 \
    } } while (0)

#define MFMA16(mh, nh, av, bv) do {                                            \
    __builtin_amdgcn_s_setprio(1);                                             \
    _Pragma("unroll") for (int _n = 0; _n < 2; ++_n)                           \
    _Pragma("unroll") for (int _m = 0; _m < 4; ++_m)                           \
    _Pragma("unroll") for (int _k = 0; _k < 2; ++_k)                           \
      acc[(mh)*4+_m][(nh)*2+_n] = __builtin_amdgcn_mfma_f32_16x16x32_bf16(     \
          av[_m][_k], bv[_n][_k], acc[(mh)*4+_m][(nh)*2+_n], 0, 0, 0);         \
    __builtin_amdgcn_s_setprio(0);                                             \
  } while (0)

#define BAR() __builtin_amdgcn_s_barrier()
#define VM4() asm volatile("s_waitcnt vmcnt(4)" ::: "memory")
#define VM0() asm volatile("s_waitcnt vmcnt(0)" ::: "memory")

#define GEMM8_BODY(NT)                                                         \
  f32x4 acc[8][4];                                                             \
  _Pragma("unroll")                                                            \
  for (int m = 0; m < 8; ++m)                                                  \
    _Pragma("unroll")                                                          \
    for (int n = 0; n < 4; ++n) acc[m][n] = (f32x4)0.0f;                       \
  short8 a[4][2], b0[2][2], b1[2][2];                                          \
  STG(0, 1, 0, 0); STG(0, 1, 1, 0); STG(0, 0, 0, 0); STG(0, 0, 1, 0);          \
  STG(1, 1, 0, 1); STG(1, 1, 1, 1);                                            \
  VM4(); BAR();                                                                \
  for (int t = 0; t < (NT); ++t) {                                             \
    const bool pf = (t < (NT) - 1);                                            \
    LDA8(a, 0, 0); LDB4(b0, 0, 0);                                             \
    STG(1, 0, 0, 2 * t + 1);                                                   \
    BAR(); MFMA16(0, 0, a, b0); BAR();                                         \
    LDB4(b1, 0, 1);                                                            \
    STG(1, 0, 1, 2 * t + 1);                                                   \
    BAR(); MFMA16(0, 1, a, b1); BAR();                                         \
    LDA8(a, 0, 1);                                                             \
    if (pf) STG(0, 1, 0, 2 * t + 2);                                           \
    BAR(); MFMA16(1, 1, a, b1); BAR();                                         \
    if (pf) STG(0, 1, 1, 2 * t + 2);                                           \
    BAR(); MFMA16(1, 0, a, b0);                                                \
    if (pf) VM4(); else VM0();                                                 \
    BAR();                                                                     \
    LDA8(a, 1, 0); LDB4(b0, 1, 0);                                             \
    if (pf) STG(0, 0, 0, 2 * t + 2);                                           \
    BAR(); MFMA16(0, 0, a, b0); BAR();                                         \
    LDB4(b1, 1, 1);                                                            \
    if (pf) STG(0, 0, 1, 2 * t + 2);                                           \
    BAR(); MFMA16(0, 1, a, b1); BAR();                                         \
    LDA8(a, 1, 1);                                                             \
    if (pf) STG(1, 1, 0, 2 * t + 3);                                           \
    BAR(); MFMA16(1, 1, a, b1); BAR();                                         \
    if (pf) STG(1, 1, 1, 2 * t + 3);                                           \
    BAR(); MFMA16(1, 0, a, b0);                                                \
    if (pf) VM4();                                                             \
    BAR();                                                                     \
  }

// ---- [y|V] = x . [M^T ; Wv^T]^T ; grid (x=row 32, y=col 8) for XCD grouping ----
__global__ __launch_bounds__(512, 2) void gemm8_yv(
    const unsigned short* __restrict__ A, const unsigned short* __restrict__ Bt,
    unsigned short* __restrict__ y, unsigned short* __restrict__ vt)
{
  const int row0 = blockIdx.x * 256;
  const int col0 = blockIdx.y * 256;
  const unsigned short* Az = A;
  const unsigned short* Bz = Bt;
  const int lda = 1024, ldb = 1024;

  __shared__ __align__(16) char lds[131072];

  const int tid = threadIdx.x;
  const int wave = tid >> 6, lane = tid & 63;
  const int wr = wave >> 2, wc = wave & 3;
  const int srow = lane >> 3, sgrp = (lane & 7) ^ srow;
  const int kbyte = (lane >> 4) * 16;

  GEMM8_BODY(8)

  const int orow = row0 + wr * 128 + ((lane >> 4) << 2);
  const int ocol = col0 + wc * 64 + (lane & 15);
  if (col0 < 1024) {
    #pragma unroll
    for (int m = 0; m < 8; ++m)
      #pragma unroll
      for (int r = 0; r < 4; ++r) {
        const int rg = orow + m * 16 + r;
        #pragma unroll
        for (int n = 0; n < 4; ++n)
          y[(long long)rg * 1024 + ocol + n * 16] = f2b(acc[m][n][r]);
      }
  } else {
    const int b = row0 >> 11;
    const int t0 = (row0 & 2047) + wr * 128 + ((lane >> 4) << 2);
    const int d0 = (col0 - 1024) + wc * 64 + (lane & 15);
    #pragma unroll
    for (int n = 0; n < 4; ++n) {
      unsigned short* vrow = vt + ((long long)b * 1024 + d0 + n * 16) * 2048 + t0;
      #pragma unroll
      for (int m = 0; m < 8; ++m) {
        short4v v;
        v[0] = (short)f2b(acc[m][n][0]);
        v[1] = (short)f2b(acc[m][n][1]);
        v[2] = (short)f2b(acc[m][n][2]);
        v[3] = (short)f2b(acc[m][n][3]);
        *(short4v*)(vrow + m * 16) = v;
      }
    }
  }
}

// ---- P = exp((y x^T)/32) causal + rowsum atomics ----
__global__ __launch_bounds__(512, 2) void gemm8_p(
    const unsigned short* __restrict__ A, const unsigned short* __restrict__ Bt,
    unsigned short* __restrict__ outp, float* __restrict__ sums)
{
  const int z = blockIdx.z;
  const int row0 = blockIdx.y * 256;
  const int col0 = blockIdx.x * 256;
  if (col0 > row0 + 255) return;

  const unsigned short* Az = A + (long long)z * (2048 * 1024);
  const unsigned short* Bz = Bt + (long long)z * (2048 * 1024);
  const int lda = 1024, ldb = 1024;

  __shared__ __align__(16) char lds[131072];

  const int tid = threadIdx.x;
  const int wave = tid >> 6, lane = tid & 63;
  const int wr = wave >> 2, wc = wave & 3;
  const int srow = lane >> 3, sgrp = (lane & 7) ^ srow;
  const int kbyte = (lane >> 4) * 16;

  GEMM8_BODY(8)

  const int orow = row0 + wr * 128 + ((lane >> 4) << 2);
  const int ocol = col0 + wc * 64 + (lane & 15);
  unsigned short* out = outp + (long long)z * (2048 * 2048);
  #pragma unroll
  for (int m = 0; m < 8; ++m)
    #pragma unroll
    for (int r = 0; r < 4; ++r) {
      const int rg = orow + m * 16 + r;
      float rs = 0.f;
      #pragma unroll
      for (int n = 0; n < 4; ++n) {
        const int cg = ocol + n * 16;
        float p = (cg > rg) ? 0.0f : __expf(acc[m][n][r] * 0.03125f);
        rs += p;
        out[(long long)rg * 2048 + cg] = f2b(p);
      }
      #pragma unroll
      for (int off = 1; off < 16; off <<= 1) rs += __shfl_xor(rs, off);
      if ((lane & 15) == 0) atomicAdd(&sums[(long long)z * 2048 + rg], rs);
    }
}

// ==================== 128x64 2-phase PV, pair-fused uniform blocks ====================
// grid (x=pair 8, y=col 16, z=batch). Each block processes TWO stripes:
// by = 15-sx (long, first) then by = sx (short) — K-tile counts sum to 34 for
// every sx, so ALL 512 blocks have identical work -> flat 2 blocks/CU, no tail.
// id%8 = sx -> both stripes of a pair stay on one XCD (L2 reuse of P rows).
__global__ __launch_bounds__(256) void gemm_pv(
    const unsigned short* __restrict__ P, const unsigned short* __restrict__ Vt,
    float* __restrict__ out, const float* __restrict__ sums)
{
  const int z = blockIdx.z;
  const int sx = blockIdx.x;
  const int col0 = blockIdx.y * 64;

  const unsigned short* Pz = P + (long long)z * (2048 * 2048);
  const unsigned short* Bz = Vt + (long long)z * (1024 * 2048);

  __shared__ __align__(16) char lds[24576];   // A [128][64] 16KB, B [64][64] 8KB

  const int tid = threadIdx.x;
  const int wave = tid >> 6;
  const int lane = tid & 63;
  const int wr = wave >> 1, wc = wave & 1;
  const int l15 = lane & 15, lk = lane >> 4;

  const int srow = lane >> 3;
  const int sgrp = (lane & 7) ^ srow;

  const int rA = wr * 64 + l15;
  const int cB = wc * 32 + l15;
  const int kb = lk * 16;
  const int xorA = (rA & 7) << 4;
  const int xorB = (cB & 7) << 4;

  const float* sz = sums + (long long)z * 2048;
  float* oz = out + (long long)z * (2048 * 1024);

  for (int half = 0; half < 2; ++half) {
    const int by = (half == 0) ? (15 - sx) : sx;
    const int row0 = by * 128;
    const int nkt = (row0 + 128) >> 6;

    f32x4 acc[4][2];
    #pragma unroll
    for (int m = 0; m < 4; ++m) { acc[m][0] = (f32x4)0.0f; acc[m][1] = (f32x4)0.0f; }

    for (int kt = 0; kt < nkt; ++kt) {
      const int kc = kt * 64;
      #pragma unroll
      for (int i = 0; i < 4; ++i) {
        const int ci = wave * 4 + i;
        gload16(Pz + (long long)(row0 + ci * 8 + srow) * 2048 + kc + sgrp * 8,
                lds + ci * 1024);
      }
      #pragma unroll
      for (int i = 0; i < 2; ++i) {
        const int ci = wave * 2 + i;
        gload16(Bz + (long long)(col0 + ci * 8 + srow) * 2048 + kc + sgrp * 8,
                lds + 16384 + ci * 1024);
      }
      __syncthreads();
      #pragma unroll
      for (int ks = 0; ks < 2; ++ks) {
        short8 af[4], bfr[2];
        #pragma unroll
        for (int m = 0; m < 4; ++m)
          af[m] = *(const short8*)(lds + (rA + m * 16) * 128 + ((ks * 64 + kb) ^ xorA));
        #pragma unroll
        for (int n = 0; n < 2; ++n)
          bfr[n] = *(const short8*)(lds + 16384 + (cB + n * 16) * 128 + ((ks * 64 + kb) ^ xorB));
        #pragma unroll
        for (int m = 0; m < 4; ++m)
          #pragma unroll
          for (int n = 0; n < 2; ++n)
            acc[m][n] = __builtin_amdgcn_mfma_f32_16x16x32_bf16(af[m], bfr[n], acc[m][n], 0, 0, 0);
      }
      __syncthreads();
    }

    const int orow = row0 + wr * 64 + lk * 4;
    const int ocol = col0 + wc * 32 + l15;
    #pragma unroll
    for (int m = 0; m < 4; ++m)
      #pragma unroll
      for (int r = 0; r < 4; ++r) {
        const int rg = orow + m * 16 + r;
        const float iv = 1.0f / sz[rg];
        #pragma unroll
        for (int n = 0; n < 2; ++n)
          oz[(long long)rg * 1024 + ocol + n * 16] = acc[m][n][r] * iv;
      }
  }
}

extern "C" void kernel_launch(void* const* d_in, const int* in_sizes, int n_in,
                              void* d_out, int out_size, void* d_ws, size_t ws_size,
                              hipStream_t stream) {
  (void)in_sizes; (void)n_in; (void)out_size; (void)ws_size;
  const float* x  = (const float*)d_in[0];
  const float* Wq = (const float*)d_in[1];
  const float* Wk = (const float*)d_in[2];
  const float* Wv = (const float*)d_in[3];
  float* out = (float*)d_out;

  char* ws = (char*)d_ws;
  unsigned short* xb  = (unsigned short*)(ws);               // 8192x1024 bf16
  unsigned short* Wt2 = (unsigned short*)(ws + 16777216);    // [2048][1024]: M^T ; Wv^T
  unsigned short* y   = (unsigned short*)(ws + 20971520);    // 8192x1024 bf16
  unsigned short* Vt  = (unsigned short*)(ws + 37748736);    // 4x1024x2048 bf16
  unsigned short* P   = (unsigned short*)(ws + 54525952);    // 4x2048x2048 bf16
  float*          sums = (float*)(ws + 88080384);            // 4x2048 fp32

  // 1. prep: cvt x, transpose Wv, M^T = Wk.Wq^T, zero sums
  prep<<<9504, 256, 0, stream>>>(x, Wq, Wk, Wv, xb, Wt2, sums);

  // 2. [y | V] = x . [M^T ; Wv^T]^T  (256 gemm8 blocks, XCD-grouped rows)
  gemm8_yv<<<dim3(32, 8), 512, 0, stream>>>(xb, Wt2, y, Vt);

  // 3. P = exp((y x^T)/32) causal, unnormalized bf16 + rowsums
  gemm8_p<<<dim3(8, 8, 4), 512, 0, stream>>>(y, xb, P, sums);

  // 4. context = (P Vt^T)/rowsum  (pair-fused 128x64 2-phase, 512 uniform blocks)
  gemm_pv<<<dim3(8, 16, 4), 256, 0, stream>>>(P, Vt, out, sums);
}

// Round 14
// 135.456 us; speedup vs baseline: 1.1347x; 1.0958x over previous
//
#include <hip/hip_runtime.h>
#include <hip/hip_bf16.h>
#include <stdint.h>

typedef short short8 __attribute__((ext_vector_type(8)));
typedef short short4v __attribute__((ext_vector_type(4)));
typedef float f32x4 __attribute__((ext_vector_type(4)));

__device__ __forceinline__ void gload16(const void* g, void* l) {
  __builtin_amdgcn_global_load_lds((const __attribute__((address_space(1))) void*)g,
                                   (__attribute__((address_space(3))) void*)l, 16, 0, 0);
}

__device__ __forceinline__ unsigned short f2b(float f) {
  unsigned int x = __float_as_uint(f);
  x += 0x7fffu + ((x >> 16) & 1u);
  return (unsigned short)(x >> 16);
}

// ==================== prep ====================
// [0,256) M^T=Wk.Wq^T (long pole, dispatched FIRST) | [256,1280) Wv->Wt2_V^T |
// [1280,9472) cvt x->xb | [9472,9504) sums=0
__global__ __launch_bounds__(256) void prep(
    const float* __restrict__ x, const float* __restrict__ Wq,
    const float* __restrict__ Wk, const float* __restrict__ Wv,
    unsigned short* __restrict__ xb, unsigned short* __restrict__ Wt2,
    float* __restrict__ sums)
{
  __shared__ __align__(16) char smem[16384];
  const int bid = blockIdx.x;
  const int tid = threadIdx.x;
  if (bid < 256) {
    // M^T = Wk . Wq^T (64x64 tile), fp32 inputs converted in-register
    const int t = bid;
    const int bx = t & 15, by = t >> 4;
    const int row0 = by * 64, col0 = bx * 64;
    const int wave = tid >> 6, lane = tid & 63;
    const int wr = wave >> 1, wc = wave & 1;
    const int l15 = lane & 15, lk = lane >> 4;
    const int sr = lane >> 3, sg = lane & 7;
    char* lA = smem;
    char* lB = smem + 8192;
    const int rA = wr * 32 + l15, cB = wc * 32 + l15;
    const int xorA = (rA & 7) << 4, xorB = (cB & 7) << 4;
    const int kb = lk * 16;
    f32x4 acc[2][2];
    #pragma unroll
    for (int m = 0; m < 2; ++m)
      #pragma unroll
      for (int n = 0; n < 2; ++n) acc[m][n] = (f32x4)0.0f;
    for (int kt = 0; kt < 16; ++kt) {
      const int kc = kt * 64;
      short8 va[2], vb[2];
      int rr[2];
      #pragma unroll
      for (int j = 0; j < 2; ++j) {
        const int ci = wave * 2 + j;
        const int r = ci * 8 + sr;
        rr[j] = r;
        const float* pa = Wk + (long long)(row0 + r) * 1024 + kc + sg * 8;
        const float* pb = Wq + (long long)(col0 + r) * 1024 + kc + sg * 8;
        const float4 a0 = *(const float4*)pa, a1 = *(const float4*)(pa + 4);
        const float4 b0 = *(const float4*)pb, b1 = *(const float4*)(pb + 4);
        va[j][0] = (short)f2b(a0.x); va[j][1] = (short)f2b(a0.y);
        va[j][2] = (short)f2b(a0.z); va[j][3] = (short)f2b(a0.w);
        va[j][4] = (short)f2b(a1.x); va[j][5] = (short)f2b(a1.y);
        va[j][6] = (short)f2b(a1.z); va[j][7] = (short)f2b(a1.w);
        vb[j][0] = (short)f2b(b0.x); vb[j][1] = (short)f2b(b0.y);
        vb[j][2] = (short)f2b(b0.z); vb[j][3] = (short)f2b(b0.w);
        vb[j][4] = (short)f2b(b1.x); vb[j][5] = (short)f2b(b1.y);
        vb[j][6] = (short)f2b(b1.z); vb[j][7] = (short)f2b(b1.w);
      }
      __syncthreads();
      #pragma unroll
      for (int j = 0; j < 2; ++j) {
        const int off = rr[j] * 128 + ((sg * 16) ^ ((rr[j] & 7) << 4));
        *(short8*)(lA + off) = va[j];
        *(short8*)(lB + off) = vb[j];
      }
      __syncthreads();
      #pragma unroll
      for (int ks = 0; ks < 2; ++ks) {
        short8 af[2], bf[2];
        #pragma unroll
        for (int m = 0; m < 2; ++m)
          af[m] = *(const short8*)(lA + (rA + m * 16) * 128 + ((ks * 64 + kb) ^ xorA));
        #pragma unroll
        for (int n = 0; n < 2; ++n)
          bf[n] = *(const short8*)(lB + (cB + n * 16) * 128 + ((ks * 64 + kb) ^ xorB));
        #pragma unroll
        for (int m = 0; m < 2; ++m)
          #pragma unroll
          for (int n = 0; n < 2; ++n)
            acc[m][n] = __builtin_amdgcn_mfma_f32_16x16x32_bf16(af[m], bf[n], acc[m][n], 0, 0, 0);
      }
    }
    const int orow = row0 + wr * 32 + lk * 4;
    const int ocol = col0 + wc * 32 + l15;
    #pragma unroll
    for (int m = 0; m < 2; ++m)
      #pragma unroll
      for (int r = 0; r < 4; ++r)
        #pragma unroll
        for (int n = 0; n < 2; ++n)
          Wt2[(long long)(orow + m * 16 + r) * 1024 + ocol + n * 16] = f2b(acc[m][n][r]);
  } else if (bid < 1280) {
    float (*tb)[33] = (float(*)[33])smem;
    const int t = bid - 256;
    const int bx = t & 31, by = t >> 5;
    const int tx = tid & 31, ty = tid >> 5;
    const int xcol = bx * 32 + tx, y0 = by * 32;
    #pragma unroll
    for (int i = 0; i < 4; ++i)
      tb[ty + i * 8][tx] = Wv[(long long)(y0 + ty + i * 8) * 1024 + xcol];
    __syncthreads();
    unsigned short* O = Wt2 + 1024 * 1024;
    const int xo = by * 32 + tx, yo0 = bx * 32;
    #pragma unroll
    for (int i = 0; i < 4; ++i)
      O[(long long)(yo0 + ty + i * 8) * 1024 + xo] = f2b(tb[tx][ty + i * 8]);
  } else if (bid < 9472) {
    const int i = (bid - 1280) * 256 + tid;
    const float4 f = ((const float4*)x)[i];
    union { unsigned short u[4]; uint2 v; } o;
    o.u[0] = f2b(f.x); o.u[1] = f2b(f.y); o.u[2] = f2b(f.z); o.u[3] = f2b(f.w);
    ((uint2*)xb)[i] = o.v;
  } else {
    const int i = (bid - 9472) * 256 + tid;
    sums[i] = 0.f;
  }
}

// ==================== 256x256 8-phase GEMM machinery (vmcnt(6), 3 half-tiles in flight) ====================
#define STG(buf, isB, half, kt) do {                                           \
    const unsigned short* _s = (isB) ? Bz : Az;                                \
    const int _ld = (isB) ? ldb : lda;                                         \
    const int _b0 = (isB) ? col0 : row0;                                       \
    char* _d = lds + (buf) * 65536 + (isB) * 32768 + (half) * 16384;           \
    _Pragma("unroll")                                                          \
    for (int _i = 0; _i < 2; ++_i) {                                           \
      const int _c = wave * 2 + _i;                                            \
      const int _row = (half) * 128 + _c * 8 + srow;                           \
      gload16(_s + (long long)(_b0 + _row) * _ld + (kt) * 64 + sgrp * 8,       \
              _d + _c * 1024);                                                 \
    } } while (0)

#define LDA8(dst, buf, mh) do {                                                \
    _Pragma("unroll")                                                          \
    for (int _m = 0; _m < 4; ++_m) {                                           \
      const int _r = wr * 128 + ((mh) * 4 + _m) * 16 + (lane & 15);            \
      const char* _p = lds + (buf) * 65536 + _r * 128;                         \
      const int _x = (_r & 7) << 4;                                            \
      dst[_m][0] = *(const short8*)(_p + ((kbyte) ^ _x));                      \
      dst[_m][1] = *(const short8*)(_p + ((64 + kbyte) ^ _x));                 \
    } } while (0)

#define LDB4(dst, buf, nh) do {                                                \
    _Pragma("unroll")                                                          \
    for (int _n = 0; _n < 2; ++_n) {                                           \
      const int _r = wc * 64 + ((nh) * 2 + _n) * 16 + (lane & 15);             \
      const char* _p = lds + (buf) * 65536 + 32768 + _r * 128;                 \
      const int _x = (_r & 7) << 4;                                            \
      dst[_n][0] = *(const short8*)(_p + ((kbyte) ^ _x));                      \
      dst[_n][1] = *(const short8*)(_p + ((64 + kbyte) ^ _x));                 \
    } } while (0)

#define MFMA16(mh, nh, av, bv) do {                                            \
    __builtin_amdgcn_s_setprio(1);                                             \
    _Pragma("unroll") for (int _n = 0; _n < 2; ++_n)                           \
    _Pragma("unroll") for (int _m = 0; _m < 4; ++_m)                           \
    _Pragma("unroll") for (int _k = 0; _k < 2; ++_k)                           \
      acc[(mh)*4+_m][(nh)*2+_n] = __builtin_amdgcn_mfma_f32_16x16x32_bf16(     \
          av[_m][_k], bv[_n][_k], acc[(mh)*4+_m][(nh)*2+_n], 0, 0, 0);         \
    __builtin_amdgcn_s_setprio(0);                                             \
  } while (0)

#define BAR() __builtin_amdgcn_s_barrier()
#define VM6() asm volatile("s_waitcnt vmcnt(6)" ::: "memory")
#define VM0() asm volatile("s_waitcnt vmcnt(0)" ::: "memory")

// Ledger (loads/thread; half-tile = 2 loads). Prologue: buf0 x4 + buf1{B0,B1,A0}
// = 7 half-tiles, VM6 -> buf0 landed. Steady iter: stages at ph1 (buf1.A1),
// ph3 (buf0.B'x2), ph4 (buf0.A0'), ph5 (buf0.A1'), ph7 (buf1.B''x2), ph8
// (buf1.A0''). At ph4: outstanding 14, VM6 drains 8 = all of buf1 (read ph5-8);
// at ph8: drains 8 = all of buf0-next (read next ph1-4). Min stage-to-drain
// distance = 3 phases. Every overwrite is after the region's last reader's
// barrier. Tail (pf=0): ph4 VM0 drains buf1.A1; ph8 nothing outstanding.
#define GEMM8_BODY(NT)                                                         \
  f32x4 acc[8][4];                                                             \
  _Pragma("unroll")                                                            \
  for (int m = 0; m < 8; ++m)                                                  \
    _Pragma("unroll")                                                          \
    for (int n = 0; n < 4; ++n) acc[m][n] = (f32x4)0.0f;                       \
  short8 a[4][2], b0[2][2], b1[2][2];                                          \
  STG(0, 1, 0, 0); STG(0, 1, 1, 0); STG(0, 0, 0, 0); STG(0, 0, 1, 0);          \
  STG(1, 1, 0, 1); STG(1, 1, 1, 1); STG(1, 0, 0, 1);                           \
  VM6(); BAR();                                                                \
  for (int t = 0; t < (NT); ++t) {                                             \
    const bool pf = (t < (NT) - 1);                                            \
    /* ph1 */                                                                  \
    LDA8(a, 0, 0); LDB4(b0, 0, 0);                                             \
    STG(1, 0, 1, 2 * t + 1);                                                   \
    BAR(); MFMA16(0, 0, a, b0); BAR();                                         \
    /* ph2 */                                                                  \
    LDB4(b1, 0, 1);                                                            \
    BAR(); MFMA16(0, 1, a, b1); BAR();                                         \
    /* ph3 */                                                                  \
    LDA8(a, 0, 1);                                                             \
    if (pf) { STG(0, 1, 0, 2 * t + 2); STG(0, 1, 1, 2 * t + 2); }              \
    BAR(); MFMA16(1, 1, a, b1); BAR();                                         \
    /* ph4 */                                                                  \
    if (pf) STG(0, 0, 0, 2 * t + 2);                                           \
    BAR(); MFMA16(1, 0, a, b0);                                                \
    if (pf) VM6(); else VM0();                                                 \
    BAR();                                                                     \
    /* ph5 */                                                                  \
    LDA8(a, 1, 0); LDB4(b0, 1, 0);                                             \
    if (pf) STG(0, 0, 1, 2 * t + 2);                                           \
    BAR(); MFMA16(0, 0, a, b0); BAR();                                         \
    /* ph6 */                                                                  \
    LDB4(b1, 1, 1);                                                            \
    BAR(); MFMA16(0, 1, a, b1); BAR();                                         \
    /* ph7 */                                                                  \
    LDA8(a, 1, 1);                                                             \
    if (pf) { STG(1, 1, 0, 2 * t + 3); STG(1, 1, 1, 2 * t + 3); }              \
    BAR(); MFMA16(1, 1, a, b1); BAR();                                         \
    /* ph8 */                                                                  \
    if (pf) STG(1, 0, 0, 2 * t + 3);                                           \
    BAR(); MFMA16(1, 0, a, b0);                                                \
    if (pf) VM6();                                                             \
    BAR();                                                                     \
  }

// ---- [y|V] = x . [M^T ; Wv^T]^T ; grid (x=row 32, y=col 8) for XCD grouping ----
__global__ __launch_bounds__(512, 2) void gemm8_yv(
    const unsigned short* __restrict__ A, const unsigned short* __restrict__ Bt,
    unsigned short* __restrict__ y, unsigned short* __restrict__ vt)
{
  const int row0 = blockIdx.x * 256;
  const int col0 = blockIdx.y * 256;
  const unsigned short* Az = A;
  const unsigned short* Bz = Bt;
  const int lda = 1024, ldb = 1024;

  __shared__ __align__(16) char lds[131072];

  const int tid = threadIdx.x;
  const int wave = tid >> 6, lane = tid & 63;
  const int wr = wave >> 2, wc = wave & 3;
  const int srow = lane >> 3, sgrp = (lane & 7) ^ srow;
  const int kbyte = (lane >> 4) * 16;

  GEMM8_BODY(8)

  const int orow = row0 + wr * 128 + ((lane >> 4) << 2);
  const int ocol = col0 + wc * 64 + (lane & 15);
  if (col0 < 1024) {
    #pragma unroll
    for (int m = 0; m < 8; ++m)
      #pragma unroll
      for (int r = 0; r < 4; ++r) {
        const int rg = orow + m * 16 + r;
        #pragma unroll
        for (int n = 0; n < 4; ++n)
          y[(long long)rg * 1024 + ocol + n * 16] = f2b(acc[m][n][r]);
      }
  } else {
    const int b = row0 >> 11;
    const int t0 = (row0 & 2047) + wr * 128 + ((lane >> 4) << 2);
    const int d0 = (col0 - 1024) + wc * 64 + (lane & 15);
    #pragma unroll
    for (int n = 0; n < 4; ++n) {
      unsigned short* vrow = vt + ((long long)b * 1024 + d0 + n * 16) * 2048 + t0;
      #pragma unroll
      for (int m = 0; m < 8; ++m) {
        short4v v;
        v[0] = (short)f2b(acc[m][n][0]);
        v[1] = (short)f2b(acc[m][n][1]);
        v[2] = (short)f2b(acc[m][n][2]);
        v[3] = (short)f2b(acc[m][n][3]);
        *(short4v*)(vrow + m * 16) = v;
      }
    }
  }
}

// ---- P = exp((y x^T)/32) causal + rowsum atomics ----
__global__ __launch_bounds__(512, 2) void gemm8_p(
    const unsigned short* __restrict__ A, const unsigned short* __restrict__ Bt,
    unsigned short* __restrict__ outp, float* __restrict__ sums)
{
  const int z = blockIdx.z;
  const int row0 = blockIdx.y * 256;
  const int col0 = blockIdx.x * 256;
  if (col0 > row0 + 255) return;

  const unsigned short* Az = A + (long long)z * (2048 * 1024);
  const unsigned short* Bz = Bt + (long long)z * (2048 * 1024);
  const int lda = 1024, ldb = 1024;

  __shared__ __align__(16) char lds[131072];

  const int tid = threadIdx.x;
  const int wave = tid >> 6, lane = tid & 63;
  const int wr = wave >> 2, wc = wave & 3;
  const int srow = lane >> 3, sgrp = (lane & 7) ^ srow;
  const int kbyte = (lane >> 4) * 16;

  GEMM8_BODY(8)

  const int orow = row0 + wr * 128 + ((lane >> 4) << 2);
  const int ocol = col0 + wc * 64 + (lane & 15);
  unsigned short* out = outp + (long long)z * (2048 * 2048);
  #pragma unroll
  for (int m = 0; m < 8; ++m)
    #pragma unroll
    for (int r = 0; r < 4; ++r) {
      const int rg = orow + m * 16 + r;
      float rs = 0.f;
      #pragma unroll
      for (int n = 0; n < 4; ++n) {
        const int cg = ocol + n * 16;
        float p = (cg > rg) ? 0.0f : __expf(acc[m][n][r] * 0.03125f);
        rs += p;
        out[(long long)rg * 2048 + cg] = f2b(p);
      }
      #pragma unroll
      for (int off = 1; off < 16; off <<= 1) rs += __shfl_xor(rs, off);
      if ((lane & 15) == 0) atomicAdd(&sums[(long long)z * 2048 + rg], rs);
    }
}

// ==================== 128x64 2-phase PV, pair-fused uniform blocks ====================
__global__ __launch_bounds__(256) void gemm_pv(
    const unsigned short* __restrict__ P, const unsigned short* __restrict__ Vt,
    float* __restrict__ out, const float* __restrict__ sums)
{
  const int z = blockIdx.z;
  const int sx = blockIdx.x;
  const int col0 = blockIdx.y * 64;

  const unsigned short* Pz = P + (long long)z * (2048 * 2048);
  const unsigned short* Bz = Vt + (long long)z * (1024 * 2048);

  __shared__ __align__(16) char lds[24576];   // A [128][64] 16KB, B [64][64] 8KB

  const int tid = threadIdx.x;
  const int wave = tid >> 6;
  const int lane = tid & 63;
  const int wr = wave >> 1, wc = wave & 1;
  const int l15 = lane & 15, lk = lane >> 4;

  const int srow = lane >> 3;
  const int sgrp = (lane & 7) ^ srow;

  const int rA = wr * 64 + l15;
  const int cB = wc * 32 + l15;
  const int kb = lk * 16;
  const int xorA = (rA & 7) << 4;
  const int xorB = (cB & 7) << 4;

  const float* sz = sums + (long long)z * 2048;
  float* oz = out + (long long)z * (2048 * 1024);

  for (int half = 0; half < 2; ++half) {
    const int by = (half == 0) ? (15 - sx) : sx;
    const int row0 = by * 128;
    const int nkt = (row0 + 128) >> 6;

    f32x4 acc[4][2];
    #pragma unroll
    for (int m = 0; m < 4; ++m) { acc[m][0] = (f32x4)0.0f; acc[m][1] = (f32x4)0.0f; }

    for (int kt = 0; kt < nkt; ++kt) {
      const int kc = kt * 64;
      #pragma unroll
      for (int i = 0; i < 4; ++i) {
        const int ci = wave * 4 + i;
        gload16(Pz + (long long)(row0 + ci * 8 + srow) * 2048 + kc + sgrp * 8,
                lds + ci * 1024);
      }
      #pragma unroll
      for (int i = 0; i < 2; ++i) {
        const int ci = wave * 2 + i;
        gload16(Bz + (long long)(col0 + ci * 8 + srow) * 2048 + kc + sgrp * 8,
                lds + 16384 + ci * 1024);
      }
      __syncthreads();
      #pragma unroll
      for (int ks = 0; ks < 2; ++ks) {
        short8 af[4], bfr[2];
        #pragma unroll
        for (int m = 0; m < 4; ++m)
          af[m] = *(const short8*)(lds + (rA + m * 16) * 128 + ((ks * 64 + kb) ^ xorA));
        #pragma unroll
        for (int n = 0; n < 2; ++n)
          bfr[n] = *(const short8*)(lds + 16384 + (cB + n * 16) * 128 + ((ks * 64 + kb) ^ xorB));
        #pragma unroll
        for (int m = 0; m < 4; ++m)
          #pragma unroll
          for (int n = 0; n < 2; ++n)
            acc[m][n] = __builtin_amdgcn_mfma_f32_16x16x32_bf16(af[m], bfr[n], acc[m][n], 0, 0, 0);
      }
      __syncthreads();
    }

    const int orow = row0 + wr * 64 + lk * 4;
    const int ocol = col0 + wc * 32 + l15;
    #pragma unroll
    for (int m = 0; m < 4; ++m)
      #pragma unroll
      for (int r = 0; r < 4; ++r) {
        const int rg = orow + m * 16 + r;
        const float iv = 1.0f / sz[rg];
        #pragma unroll
        for (int n = 0; n < 2; ++n)
          oz[(long long)rg * 1024 + ocol + n * 16] = acc[m][n][r] * iv;
      }
  }
}

extern "C" void kernel_launch(void* const* d_in, const int* in_sizes, int n_in,
                              void* d_out, int out_size, void* d_ws, size_t ws_size,
                              hipStream_t stream) {
  (void)in_sizes; (void)n_in; (void)out_size; (void)ws_size;
  const float* x  = (const float*)d_in[0];
  const float* Wq = (const float*)d_in[1];
  const float* Wk = (const float*)d_in[2];
  const float* Wv = (const float*)d_in[3];
  float* out = (float*)d_out;

  char* ws = (char*)d_ws;
  unsigned short* xb  = (unsigned short*)(ws);               // 8192x1024 bf16
  unsigned short* Wt2 = (unsigned short*)(ws + 16777216);    // [2048][1024]: M^T ; Wv^T
  unsigned short* y   = (unsigned short*)(ws + 20971520);    // 8192x1024 bf16
  unsigned short* Vt  = (unsigned short*)(ws + 37748736);    // 4x1024x2048 bf16
  unsigned short* P   = (unsigned short*)(ws + 54525952);    // 4x2048x2048 bf16
  float*          sums = (float*)(ws + 88080384);            // 4x2048 fp32

  // 1. prep: M^T GEMM first (long pole), Wv transpose, cvt x, zero sums
  prep<<<9504, 256, 0, stream>>>(x, Wq, Wk, Wv, xb, Wt2, sums);

  // 2. [y | V] = x . [M^T ; Wv^T]^T  (256 gemm8 blocks, XCD-grouped rows)
  gemm8_yv<<<dim3(32, 8), 512, 0, stream>>>(xb, Wt2, y, Vt);

  // 3. P = exp((y x^T)/32) causal, unnormalized bf16 + rowsums
  gemm8_p<<<dim3(8, 8, 4), 512, 0, stream>>>(y, xb, P, sums);

  // 4. context = (P Vt^T)/rowsum  (pair-fused 128x64 2-phase, 512 uniform blocks)
  gemm_pv<<<dim3(8, 16, 4), 256, 0, stream>>>(P, Vt, out, sums);
}

// Round 15
// 134.686 us; speedup vs baseline: 1.1412x; 1.0057x over previous
//
#include <hip/hip_runtime.h>
#include <hip/hip_bf16.h>
#include <stdint.h>

typedef short short8 __attribute__((ext_vector_type(8)));
typedef short short4v __attribute__((ext_vector_type(4)));
typedef float f32x4 __attribute__((ext_vector_type(4)));

__device__ __forceinline__ void gload16(const void* g, void* l) {
  __builtin_amdgcn_global_load_lds((const __attribute__((address_space(1))) void*)g,
                                   (__attribute__((address_space(3))) void*)l, 16, 0, 0);
}

__device__ __forceinline__ unsigned short f2b(float f) {
  unsigned int x = __float_as_uint(f);
  x += 0x7fffu + ((x >> 16) & 1u);
  return (unsigned short)(x >> 16);
}

// ==================== prep ====================
// [0,256) M^T=Wk.Wq^T (long pole, FIRST) | [256,1280) Wv->Wt2_V^T |
// [1280,9472) cvt x->xb | [9472,9504) sums=0
__global__ __launch_bounds__(256) void prep(
    const float* __restrict__ x, const float* __restrict__ Wq,
    const float* __restrict__ Wk, const float* __restrict__ Wv,
    unsigned short* __restrict__ xb, unsigned short* __restrict__ Wt2,
    float* __restrict__ sums)
{
  __shared__ __align__(16) char smem[16384];
  const int bid = blockIdx.x;
  const int tid = threadIdx.x;
  if (bid < 256) {
    const int t = bid;
    const int bx = t & 15, by = t >> 4;
    const int row0 = by * 64, col0 = bx * 64;
    const int wave = tid >> 6, lane = tid & 63;
    const int wr = wave >> 1, wc = wave & 1;
    const int l15 = lane & 15, lk = lane >> 4;
    const int sr = lane >> 3, sg = lane & 7;
    char* lA = smem;
    char* lB = smem + 8192;
    const int rA = wr * 32 + l15, cB = wc * 32 + l15;
    const int xorA = (rA & 7) << 4, xorB = (cB & 7) << 4;
    const int kb = lk * 16;
    f32x4 acc[2][2];
    #pragma unroll
    for (int m = 0; m < 2; ++m)
      #pragma unroll
      for (int n = 0; n < 2; ++n) acc[m][n] = (f32x4)0.0f;
    for (int kt = 0; kt < 16; ++kt) {
      const int kc = kt * 64;
      short8 va[2], vb[2];
      int rr[2];
      #pragma unroll
      for (int j = 0; j < 2; ++j) {
        const int ci = wave * 2 + j;
        const int r = ci * 8 + sr;
        rr[j] = r;
        const float* pa = Wk + (long long)(row0 + r) * 1024 + kc + sg * 8;
        const float* pb = Wq + (long long)(col0 + r) * 1024 + kc + sg * 8;
        const float4 a0 = *(const float4*)pa, a1 = *(const float4*)(pa + 4);
        const float4 b0 = *(const float4*)pb, b1 = *(const float4*)(pb + 4);
        va[j][0] = (short)f2b(a0.x); va[j][1] = (short)f2b(a0.y);
        va[j][2] = (short)f2b(a0.z); va[j][3] = (short)f2b(a0.w);
        va[j][4] = (short)f2b(a1.x); va[j][5] = (short)f2b(a1.y);
        va[j][6] = (short)f2b(a1.z); va[j][7] = (short)f2b(a1.w);
        vb[j][0] = (short)f2b(b0.x); vb[j][1] = (short)f2b(b0.y);
        vb[j][2] = (short)f2b(b0.z); vb[j][3] = (short)f2b(b0.w);
        vb[j][4] = (short)f2b(b1.x); vb[j][5] = (short)f2b(b1.y);
        vb[j][6] = (short)f2b(b1.z); vb[j][7] = (short)f2b(b1.w);
      }
      __syncthreads();
      #pragma unroll
      for (int j = 0; j < 2; ++j) {
        const int off = rr[j] * 128 + ((sg * 16) ^ ((rr[j] & 7) << 4));
        *(short8*)(lA + off) = va[j];
        *(short8*)(lB + off) = vb[j];
      }
      __syncthreads();
      #pragma unroll
      for (int ks = 0; ks < 2; ++ks) {
        short8 af[2], bf[2];
        #pragma unroll
        for (int m = 0; m < 2; ++m)
          af[m] = *(const short8*)(lA + (rA + m * 16) * 128 + ((ks * 64 + kb) ^ xorA));
        #pragma unroll
        for (int n = 0; n < 2; ++n)
          bf[n] = *(const short8*)(lB + (cB + n * 16) * 128 + ((ks * 64 + kb) ^ xorB));
        #pragma unroll
        for (int m = 0; m < 2; ++m)
          #pragma unroll
          for (int n = 0; n < 2; ++n)
            acc[m][n] = __builtin_amdgcn_mfma_f32_16x16x32_bf16(af[m], bf[n], acc[m][n], 0, 0, 0);
      }
    }
    const int orow = row0 + wr * 32 + lk * 4;
    const int ocol = col0 + wc * 32 + l15;
    #pragma unroll
    for (int m = 0; m < 2; ++m)
      #pragma unroll
      for (int r = 0; r < 4; ++r)
        #pragma unroll
        for (int n = 0; n < 2; ++n)
          Wt2[(long long)(orow + m * 16 + r) * 1024 + ocol + n * 16] = f2b(acc[m][n][r]);
  } else if (bid < 1280) {
    float (*tb)[33] = (float(*)[33])smem;
    const int t = bid - 256;
    const int bx = t & 31, by = t >> 5;
    const int tx = tid & 31, ty = tid >> 5;
    const int xcol = bx * 32 + tx, y0 = by * 32;
    #pragma unroll
    for (int i = 0; i < 4; ++i)
      tb[ty + i * 8][tx] = Wv[(long long)(y0 + ty + i * 8) * 1024 + xcol];
    __syncthreads();
    unsigned short* O = Wt2 + 1024 * 1024;
    const int xo = by * 32 + tx, yo0 = bx * 32;
    #pragma unroll
    for (int i = 0; i < 4; ++i)
      O[(long long)(yo0 + ty + i * 8) * 1024 + xo] = f2b(tb[tx][ty + i * 8]);
  } else if (bid < 9472) {
    const int i = (bid - 1280) * 256 + tid;
    const float4 f = ((const float4*)x)[i];
    union { unsigned short u[4]; uint2 v; } o;
    o.u[0] = f2b(f.x); o.u[1] = f2b(f.y); o.u[2] = f2b(f.z); o.u[3] = f2b(f.w);
    ((uint2*)xb)[i] = o.v;
  } else {
    const int i = (bid - 9472) * 256 + tid;
    sums[i] = 0.f;
  }
}

// ==================== 256x256 8-phase GEMM machinery (vmcnt(6)) ====================
#define STG(buf, isB, half, kt) do {                                           \
    const unsigned short* _s = (isB) ? Bz : Az;                                \
    const int _ld = (isB) ? ldb : lda;                                         \
    const int _b0 = (isB) ? col0 : row0;                                       \
    char* _d = lds + (buf) * 65536 + (isB) * 32768 + (half) * 16384;           \
    _Pragma("unroll")                                                          \
    for (int _i = 0; _i < 2; ++_i) {                                           \
      const int _c = wave * 2 + _i;                                            \
      const int _row = (half) * 128 + _c * 8 + srow;                           \
      gload16(_s + (long long)(_b0 + _row) * _ld + (kt) * 64 + sgrp * 8,       \
              _d + _c * 1024);                                                 \
    } } while (0)

#define LDA8(dst, buf, mh) do {                                                \
    _Pragma("unroll")                                                          \
    for (int _m = 0; _m < 4; ++_m) {                                           \
      const int _r = wr * 128 + ((mh) * 4 + _m) * 16 + (lane & 15);            \
      const char* _p = lds + (buf) * 65536 + _r * 128;                         \
      const int _x = (_r & 7) << 4;                                            \
      dst[_m][0] = *(const short8*)(_p + ((kbyte) ^ _x));                      \
      dst[_m][1] = *(const short8*)(_p + ((64 + kbyte) ^ _x));                 \
    } } while (0)

#define LDB4(dst, buf, nh) do {                                                \
    _Pragma("unroll")                                                          \
    for (int _n = 0; _n < 2; ++_n) {                                           \
      const int _r = wc * 64 + ((nh) * 2 + _n) * 16 + (lane & 15);             \
      const char* _p = lds + (buf) * 65536 + 32768 + _r * 128;                 \
      const int _x = (_r & 7) << 4;                                            \
      dst[_n][0] = *(const short8*)(_p + ((kbyte) ^ _x));                      \
      dst[_n][1] = *(const short8*)(_p + ((64 + kbyte) ^ _x));                 \
    } } while (0)

#define MFMA16(mh, nh, av, bv) do {                                            \
    __builtin_amdgcn_s_setprio(1);                                             \
    _Pragma("unroll") for (int _n = 0; _n < 2; ++_n)                           \
    _Pragma("unroll") for (int _m = 0; _m < 4; ++_m)                           \
    _Pragma("unroll") for (int _k = 0; _k < 2; ++_k)                           \
      acc[(mh)*4+_m][(nh)*2+_n] = __builtin_amdgcn_mfma_f32_16x16x32_bf16(     \
          av[_m][_k], bv[_n][_k], acc[(mh)*4+_m][(nh)*2+_n], 0, 0, 0);         \
    __builtin_amdgcn_s_setprio(0);                                             \
  } while (0)

#define BAR() __builtin_amdgcn_s_barrier()
#define VM6() asm volatile("s_waitcnt vmcnt(6)" ::: "memory")
#define VM0() asm volatile("s_waitcnt vmcnt(0)" ::: "memory")

#define GEMM8_BODY(NT)                                                         \
  f32x4 acc[8][4];                                                             \
  _Pragma("unroll")                                                            \
  for (int m = 0; m < 8; ++m)                                                  \
    _Pragma("unroll")                                                          \
    for (int n = 0; n < 4; ++n) acc[m][n] = (f32x4)0.0f;                       \
  short8 a[4][2], b0[2][2], b1[2][2];                                          \
  STG(0, 1, 0, 0); STG(0, 1, 1, 0); STG(0, 0, 0, 0); STG(0, 0, 1, 0);          \
  STG(1, 1, 0, 1); STG(1, 1, 1, 1); STG(1, 0, 0, 1);                           \
  VM6(); BAR();                                                                \
  for (int t = 0; t < (NT); ++t) {                                             \
    const bool pf = (t < (NT) - 1);                                            \
    /* ph1 */                                                                  \
    LDA8(a, 0, 0); LDB4(b0, 0, 0);                                             \
    STG(1, 0, 1, 2 * t + 1);                                                   \
    BAR(); MFMA16(0, 0, a, b0); BAR();                                         \
    /* ph2 */                                                                  \
    LDB4(b1, 0, 1);                                                            \
    BAR(); MFMA16(0, 1, a, b1); BAR();                                         \
    /* ph3 */                                                                  \
    LDA8(a, 0, 1);                                                             \
    if (pf) { STG(0, 1, 0, 2 * t + 2); STG(0, 1, 1, 2 * t + 2); }              \
    BAR(); MFMA16(1, 1, a, b1); BAR();                                         \
    /* ph4 */                                                                  \
    if (pf) STG(0, 0, 0, 2 * t + 2);                                           \
    BAR(); MFMA16(1, 0, a, b0);                                                \
    if (pf) VM6(); else VM0();                                                 \
    BAR();                                                                     \
    /* ph5 */                                                                  \
    LDA8(a, 1, 0); LDB4(b0, 1, 0);                                             \
    if (pf) STG(0, 0, 1, 2 * t + 2);                                           \
    BAR(); MFMA16(0, 0, a, b0); BAR();                                         \
    /* ph6 */                                                                  \
    LDB4(b1, 1, 1);                                                            \
    BAR(); MFMA16(0, 1, a, b1); BAR();                                         \
    /* ph7 */                                                                  \
    LDA8(a, 1, 1);                                                             \
    if (pf) { STG(1, 1, 0, 2 * t + 3); STG(1, 1, 1, 2 * t + 3); }              \
    BAR(); MFMA16(1, 1, a, b1); BAR();                                         \
    /* ph8 */                                                                  \
    if (pf) STG(1, 0, 0, 2 * t + 3);                                           \
    BAR(); MFMA16(1, 0, a, b0);                                                \
    if (pf) VM6();                                                             \
    BAR();                                                                     \
  }

// ---- [y|V] = x . [M^T ; Wv^T]^T ; grid (x=row 32, y=col 8) for XCD grouping.
// V-blocks write Vt via LDS bounce: scattered 8B stores -> coalesced dwordx4.
__global__ __launch_bounds__(512, 2) void gemm8_yv(
    const unsigned short* __restrict__ A, const unsigned short* __restrict__ Bt,
    unsigned short* __restrict__ y, unsigned short* __restrict__ vt)
{
  const int row0 = blockIdx.x * 256;
  const int col0 = blockIdx.y * 256;
  const unsigned short* Az = A;
  const unsigned short* Bz = Bt;
  const int lda = 1024, ldb = 1024;

  __shared__ __align__(16) char lds[131072];

  const int tid = threadIdx.x;
  const int wave = tid >> 6, lane = tid & 63;
  const int wr = wave >> 2, wc = wave & 3;
  const int srow = lane >> 3, sgrp = (lane & 7) ^ srow;
  const int kbyte = (lane >> 4) * 16;

  GEMM8_BODY(8)

  if (col0 < 1024) {
    const int orow = row0 + wr * 128 + ((lane >> 4) << 2);
    const int ocol = col0 + wc * 64 + (lane & 15);
    #pragma unroll
    for (int m = 0; m < 8; ++m)
      #pragma unroll
      for (int r = 0; r < 4; ++r) {
        const int rg = orow + m * 16 + r;
        #pragma unroll
        for (int n = 0; n < 4; ++n)
          y[(long long)rg * 1024 + ocol + n * 16] = f2b(acc[m][n][r]);
      }
  } else {
    // transpose tile in LDS: [d 256][t 256] bf16, XOR-swizzled rows (2-way free)
    const int b = row0 >> 11;
    const int t_base = row0 & 2047;
    const int d_base = col0 - 1024;
    const int t_loc0 = wr * 128 + ((lane >> 4) << 2);
    const int d_loc0 = wc * 64 + (lane & 15);
    #pragma unroll
    for (int n = 0; n < 4; ++n) {
      const int d = d_loc0 + n * 16;
      const int sw = (d & 7) << 4;
      #pragma unroll
      for (int m = 0; m < 8; ++m) {
        short4v v;
        v[0] = (short)f2b(acc[m][n][0]);
        v[1] = (short)f2b(acc[m][n][1]);
        v[2] = (short)f2b(acc[m][n][2]);
        v[3] = (short)f2b(acc[m][n][3]);
        const int t = t_loc0 + m * 16;
        *(short4v*)(lds + d * 512 + ((t * 2) ^ sw)) = v;
      }
    }
    __syncthreads();
    #pragma unroll
    for (int it = 0; it < 16; ++it) {
      const int dl = it * 16 + (tid >> 5);
      const int tb = (tid & 31) * 16;  // byte offset within 512B t-row
      const uint4 v = *(const uint4*)(lds + dl * 512 + (tb ^ ((dl & 7) << 4)));
      *(uint4*)((char*)(vt + ((long long)(b * 1024 + d_base + dl) * 2048 + t_base)) + tb) = v;
    }
  }
}

// ---- P = exp((y x^T)/32) causal + rowsum atomics.
// grid (x=by 8, y=bx 8, z): id%8 = by -> same-stripe blocks share one XCD (y-stripe L2 reuse)
__global__ __launch_bounds__(512, 2) void gemm8_p(
    const unsigned short* __restrict__ A, const unsigned short* __restrict__ Bt,
    unsigned short* __restrict__ outp, float* __restrict__ sums)
{
  const int z = blockIdx.z;
  const int row0 = blockIdx.x * 256;
  const int col0 = blockIdx.y * 256;
  if (col0 > row0 + 255) return;

  const unsigned short* Az = A + (long long)z * (2048 * 1024);
  const unsigned short* Bz = Bt + (long long)z * (2048 * 1024);
  const int lda = 1024, ldb = 1024;

  __shared__ __align__(16) char lds[131072];

  const int tid = threadIdx.x;
  const int wave = tid >> 6, lane = tid & 63;
  const int wr = wave >> 2, wc = wave & 3;
  const int srow = lane >> 3, sgrp = (lane & 7) ^ srow;
  const int kbyte = (lane >> 4) * 16;

  GEMM8_BODY(8)

  const int orow = row0 + wr * 128 + ((lane >> 4) << 2);
  const int ocol = col0 + wc * 64 + (lane & 15);
  unsigned short* out = outp + (long long)z * (2048 * 2048);
  #pragma unroll
  for (int m = 0; m < 8; ++m)
    #pragma unroll
    for (int r = 0; r < 4; ++r) {
      const int rg = orow + m * 16 + r;
      float rs = 0.f;
      #pragma unroll
      for (int n = 0; n < 4; ++n) {
        const int cg = ocol + n * 16;
        float p = (cg > rg) ? 0.0f : __expf(acc[m][n][r] * 0.03125f);
        rs += p;
        out[(long long)rg * 2048 + cg] = f2b(p);
      }
      #pragma unroll
      for (int off = 1; off < 16; off <<= 1) rs += __shfl_xor(rs, off);
      if ((lane & 15) == 0) atomicAdd(&sums[(long long)z * 2048 + rg], rs);
    }
}

// ==================== 128x64 2-phase PV, pair-fused uniform blocks ====================
__global__ __launch_bounds__(256) void gemm_pv(
    const unsigned short* __restrict__ P, const unsigned short* __restrict__ Vt,
    float* __restrict__ out, const float* __restrict__ sums)
{
  const int z = blockIdx.z;
  const int sx = blockIdx.x;
  const int col0 = blockIdx.y * 64;

  const unsigned short* Pz = P + (long long)z * (2048 * 2048);
  const unsigned short* Bz = Vt + (long long)z * (1024 * 2048);

  __shared__ __align__(16) char lds[24576];   // A [128][64] 16KB, B [64][64] 8KB

  const int tid = threadIdx.x;
  const int wave = tid >> 6;
  const int lane = tid & 63;
  const int wr = wave >> 1, wc = wave & 1;
  const int l15 = lane & 15, lk = lane >> 4;

  const int srow = lane >> 3;
  const int sgrp = (lane & 7) ^ srow;

  const int rA = wr * 64 + l15;
  const int cB = wc * 32 + l15;
  const int kb = lk * 16;
  const int xorA = (rA & 7) << 4;
  const int xorB = (cB & 7) << 4;

  const float* sz = sums + (long long)z * 2048;
  float* oz = out + (long long)z * (2048 * 1024);

  for (int half = 0; half < 2; ++half) {
    const int by = (half == 0) ? (15 - sx) : sx;
    const int row0 = by * 128;
    const int nkt = (row0 + 128) >> 6;

    f32x4 acc[4][2];
    #pragma unroll
    for (int m = 0; m < 4; ++m) { acc[m][0] = (f32x4)0.0f; acc[m][1] = (f32x4)0.0f; }

    for (int kt = 0; kt < nkt; ++kt) {
      const int kc = kt * 64;
      #pragma unroll
      for (int i = 0; i < 4; ++i) {
        const int ci = wave * 4 + i;
        gload16(Pz + (long long)(row0 + ci * 8 + srow) * 2048 + kc + sgrp * 8,
                lds + ci * 1024);
      }
      #pragma unroll
      for (int i = 0; i < 2; ++i) {
        const int ci = wave * 2 + i;
        gload16(Bz + (long long)(col0 + ci * 8 + srow) * 2048 + kc + sgrp * 8,
                lds + 16384 + ci * 1024);
      }
      __syncthreads();
      #pragma unroll
      for (int ks = 0; ks < 2; ++ks) {
        short8 af[4], bfr[2];
        #pragma unroll
        for (int m = 0; m < 4; ++m)
          af[m] = *(const short8*)(lds + (rA + m * 16) * 128 + ((ks * 64 + kb) ^ xorA));
        #pragma unroll
        for (int n = 0; n < 2; ++n)
          bfr[n] = *(const short8*)(lds + 16384 + (cB + n * 16) * 128 + ((ks * 64 + kb) ^ xorB));
        #pragma unroll
        for (int m = 0; m < 4; ++m)
          #pragma unroll
          for (int n = 0; n < 2; ++n)
            acc[m][n] = __builtin_amdgcn_mfma_f32_16x16x32_bf16(af[m], bfr[n], acc[m][n], 0, 0, 0);
      }
      __syncthreads();
    }

    const int orow = row0 + wr * 64 + lk * 4;
    const int ocol = col0 + wc * 32 + l15;
    #pragma unroll
    for (int m = 0; m < 4; ++m)
      #pragma unroll
      for (int r = 0; r < 4; ++r) {
        const int rg = orow + m * 16 + r;
        const float iv = 1.0f / sz[rg];
        #pragma unroll
        for (int n = 0; n < 2; ++n)
          oz[(long long)rg * 1024 + ocol + n * 16] = acc[m][n][r] * iv;
      }
  }
}

extern "C" void kernel_launch(void* const* d_in, const int* in_sizes, int n_in,
                              void* d_out, int out_size, void* d_ws, size_t ws_size,
                              hipStream_t stream) {
  (void)in_sizes; (void)n_in; (void)out_size; (void)ws_size;
  const float* x  = (const float*)d_in[0];
  const float* Wq = (const float*)d_in[1];
  const float* Wk = (const float*)d_in[2];
  const float* Wv = (const float*)d_in[3];
  float* out = (float*)d_out;

  char* ws = (char*)d_ws;
  unsigned short* xb  = (unsigned short*)(ws);               // 8192x1024 bf16
  unsigned short* Wt2 = (unsigned short*)(ws + 16777216);    // [2048][1024]: M^T ; Wv^T
  unsigned short* y   = (unsigned short*)(ws + 20971520);    // 8192x1024 bf16
  unsigned short* Vt  = (unsigned short*)(ws + 37748736);    // 4x1024x2048 bf16
  unsigned short* P   = (unsigned short*)(ws + 54525952);    // 4x2048x2048 bf16
  float*          sums = (float*)(ws + 88080384);            // 4x2048 fp32

  // 1. prep: M^T GEMM first (long pole), Wv transpose, cvt x, zero sums
  prep<<<9504, 256, 0, stream>>>(x, Wq, Wk, Wv, xb, Wt2, sums);

  // 2. [y | V] = x . [M^T ; Wv^T]^T  (256 gemm8 blocks; Vt via LDS-bounce)
  gemm8_yv<<<dim3(32, 8), 512, 0, stream>>>(xb, Wt2, y, Vt);

  // 3. P = exp((y x^T)/32) causal + rowsums  (grid swapped: id%8 = stripe -> XCD-local y)
  gemm8_p<<<dim3(8, 8, 4), 512, 0, stream>>>(y, xb, P, sums);

  // 4. context = (P Vt^T)/rowsum  (pair-fused 128x64 2-phase, 512 uniform blocks)
  gemm_pv<<<dim3(8, 16, 4), 256, 0, stream>>>(P, Vt, out, sums);
}

// Round 16
// 129.439 us; speedup vs baseline: 1.1875x; 1.0405x over previous
//
#include <hip/hip_runtime.h>
#include <hip/hip_bf16.h>
#include <stdint.h>

typedef short short8 __attribute__((ext_vector_type(8)));
typedef short short4v __attribute__((ext_vector_type(4)));
typedef float f32x4 __attribute__((ext_vector_type(4)));

__device__ __forceinline__ void gload16(const void* g, void* l) {
  __builtin_amdgcn_global_load_lds((const __attribute__((address_space(1))) void*)g,
                                   (__attribute__((address_space(3))) void*)l, 16, 0, 0);
}

__device__ __forceinline__ unsigned short f2b(float f) {
  unsigned int x = __float_as_uint(f);
  x += 0x7fffu + ((x >> 16) & 1u);
  return (unsigned short)(x >> 16);
}

// ==================== prep ====================
// [0,256) M^T=Wk.Wq^T (long pole, FIRST, prefetched) | [256,1280) Wv->Wt2_V^T |
// [1280,9472) cvt x->xb | [9472,9504) sums=0
__global__ __launch_bounds__(256) void prep(
    const float* __restrict__ x, const float* __restrict__ Wq,
    const float* __restrict__ Wk, const float* __restrict__ Wv,
    unsigned short* __restrict__ xb, unsigned short* __restrict__ Wt2,
    float* __restrict__ sums)
{
  __shared__ __align__(16) char smem[16384];
  const int bid = blockIdx.x;
  const int tid = threadIdx.x;
  if (bid < 256) {
    const int t = bid;
    const int bx = t & 15, by = t >> 4;
    const int row0 = by * 64, col0 = bx * 64;
    const int wave = tid >> 6, lane = tid & 63;
    const int wr = wave >> 1, wc = wave & 1;
    const int l15 = lane & 15, lk = lane >> 4;
    const int sr = lane >> 3, sg = lane & 7;
    char* lA = smem;
    char* lB = smem + 8192;
    const int rA = wr * 32 + l15, cB = wc * 32 + l15;
    const int xorA = (rA & 7) << 4, xorB = (cB & 7) << 4;
    const int kb = lk * 16;
    const int rr0 = (wave * 2 + 0) * 8 + sr;
    const int rr1 = (wave * 2 + 1) * 8 + sr;
    f32x4 acc[2][2];
    #pragma unroll
    for (int m = 0; m < 2; ++m)
      #pragma unroll
      for (int n = 0; n < 2; ++n) acc[m][n] = (f32x4)0.0f;

    // 2-deep pipelined loads: raw float4 ping-pong, convert at write time
    float4 rA0[2][2], rA1[2][2], rB0[2][2], rB1[2][2];   // [buf][j]
#define MISSUE(buf, kt) do {                                                  \
      _Pragma("unroll")                                                       \
      for (int _j = 0; _j < 2; ++_j) {                                        \
        const int _r = _j ? rr1 : rr0;                                        \
        const float* _pa = Wk + (long long)(row0 + _r) * 1024 + (kt) * 64 + sg * 8; \
        const float* _pb = Wq + (long long)(col0 + _r) * 1024 + (kt) * 64 + sg * 8; \
        rA0[buf][_j] = *(const float4*)_pa;  rA1[buf][_j] = *(const float4*)(_pa + 4); \
        rB0[buf][_j] = *(const float4*)_pb;  rB1[buf][_j] = *(const float4*)(_pb + 4); \
      } } while (0)

    MISSUE(0, 0);
    #pragma unroll
    for (int kt = 0; kt < 16; ++kt) {
      const int cb = kt & 1;
      if (kt < 15) MISSUE(cb ^ 1, kt + 1);   // issue next chunk early (hides latency)
      __syncthreads();                        // prev iter's LDS reads complete
      #pragma unroll
      for (int j = 0; j < 2; ++j) {
        const int r = j ? rr1 : rr0;
        short8 va, vb;
        va[0] = (short)f2b(rA0[cb][j].x); va[1] = (short)f2b(rA0[cb][j].y);
        va[2] = (short)f2b(rA0[cb][j].z); va[3] = (short)f2b(rA0[cb][j].w);
        va[4] = (short)f2b(rA1[cb][j].x); va[5] = (short)f2b(rA1[cb][j].y);
        va[6] = (short)f2b(rA1[cb][j].z); va[7] = (short)f2b(rA1[cb][j].w);
        vb[0] = (short)f2b(rB0[cb][j].x); vb[1] = (short)f2b(rB0[cb][j].y);
        vb[2] = (short)f2b(rB0[cb][j].z); vb[3] = (short)f2b(rB0[cb][j].w);
        vb[4] = (short)f2b(rB1[cb][j].x); vb[5] = (short)f2b(rB1[cb][j].y);
        vb[6] = (short)f2b(rB1[cb][j].z); vb[7] = (short)f2b(rB1[cb][j].w);
        const int off = r * 128 + ((sg * 16) ^ ((r & 7) << 4));
        *(short8*)(lA + off) = va;
        *(short8*)(lB + off) = vb;
      }
      __syncthreads();
      #pragma unroll
      for (int ks = 0; ks < 2; ++ks) {
        short8 af[2], bf[2];
        #pragma unroll
        for (int m = 0; m < 2; ++m)
          af[m] = *(const short8*)(lA + (rA + m * 16) * 128 + ((ks * 64 + kb) ^ xorA));
        #pragma unroll
        for (int n = 0; n < 2; ++n)
          bf[n] = *(const short8*)(lB + (cB + n * 16) * 128 + ((ks * 64 + kb) ^ xorB));
        #pragma unroll
        for (int m = 0; m < 2; ++m)
          #pragma unroll
          for (int n = 0; n < 2; ++n)
            acc[m][n] = __builtin_amdgcn_mfma_f32_16x16x32_bf16(af[m], bf[n], acc[m][n], 0, 0, 0);
      }
    }
    const int orow = row0 + wr * 32 + lk * 4;
    const int ocol = col0 + wc * 32 + l15;
    #pragma unroll
    for (int m = 0; m < 2; ++m)
      #pragma unroll
      for (int r = 0; r < 4; ++r)
        #pragma unroll
        for (int n = 0; n < 2; ++n)
          Wt2[(long long)(orow + m * 16 + r) * 1024 + ocol + n * 16] = f2b(acc[m][n][r]);
  } else if (bid < 1280) {
    float (*tb)[33] = (float(*)[33])smem;
    const int t = bid - 256;
    const int bx = t & 31, by = t >> 5;
    const int tx = tid & 31, ty = tid >> 5;
    const int xcol = bx * 32 + tx, y0 = by * 32;
    #pragma unroll
    for (int i = 0; i < 4; ++i)
      tb[ty + i * 8][tx] = Wv[(long long)(y0 + ty + i * 8) * 1024 + xcol];
    __syncthreads();
    unsigned short* O = Wt2 + 1024 * 1024;
    const int xo = by * 32 + tx, yo0 = bx * 32;
    #pragma unroll
    for (int i = 0; i < 4; ++i)
      O[(long long)(yo0 + ty + i * 8) * 1024 + xo] = f2b(tb[tx][ty + i * 8]);
  } else if (bid < 9472) {
    const int i = (bid - 1280) * 256 + tid;
    const float4 f = ((const float4*)x)[i];
    union { unsigned short u[4]; uint2 v; } o;
    o.u[0] = f2b(f.x); o.u[1] = f2b(f.y); o.u[2] = f2b(f.z); o.u[3] = f2b(f.w);
    ((uint2*)xb)[i] = o.v;
  } else {
    const int i = (bid - 9472) * 256 + tid;
    sums[i] = 0.f;
  }
}

// ==================== 256x256 8-phase GEMM machinery (vmcnt(6)) ====================
#define STG(buf, isB, half, kt) do {                                           \
    const unsigned short* _s = (isB) ? Bz : Az;                                \
    const int _ld = (isB) ? ldb : lda;                                         \
    const int _b0 = (isB) ? col0 : row0;                                       \
    char* _d = lds + (buf) * 65536 + (isB) * 32768 + (half) * 16384;           \
    _Pragma("unroll")                                                          \
    for (int _i = 0; _i < 2; ++_i) {                                           \
      const int _c = wave * 2 + _i;                                            \
      const int _row = (half) * 128 + _c * 8 + srow;                           \
      gload16(_s + (long long)(_b0 + _row) * _ld + (kt) * 64 + sgrp * 8,       \
              _d + _c * 1024);                                                 \
    } } while (0)

#define LDA8(dst, buf, mh) do {                                                \
    _Pragma("unroll")                                                          \
    for (int _m = 0; _m < 4; ++_m) {                                           \
      const int _r = wr * 128 + ((mh) * 4 + _m) * 16 + (lane & 15);            \
      const char* _p = lds + (buf) * 65536 + _r * 128;                         \
      const int _x = (_r & 7) << 4;                                            \
      dst[_m][0] = *(const short8*)(_p + ((kbyte) ^ _x));                      \
      dst[_m][1] = *(const short8*)(_p + ((64 + kbyte) ^ _x));                 \
    } } while (0)

#define LDB4(dst, buf, nh) do {                                                \
    _Pragma("unroll")                                                          \
    for (int _n = 0; _n < 2; ++_n) {                                           \
      const int _r = wc * 64 + ((nh) * 2 + _n) * 16 + (lane & 15);             \
      const char* _p = lds + (buf) * 65536 + 32768 + _r * 128;                 \
      const int _x = (_r & 7) << 4;                                            \
      dst[_n][0] = *(const short8*)(_p + ((kbyte) ^ _x));                      \
      dst[_n][1] = *(const short8*)(_p + ((64 + kbyte) ^ _x));                 \
    } } while (0)

#define MFMA16(mh, nh, av, bv) do {                                            \
    __builtin_amdgcn_s_setprio(1);                                             \
    _Pragma("unroll") for (int _n = 0; _n < 2; ++_n)                           \
    _Pragma("unroll") for (int _m = 0; _m < 4; ++_m)                           \
    _Pragma("unroll") for (int _k = 0; _k < 2; ++_k)                           \
      acc[(mh)*4+_m][(nh)*2+_n] = __builtin_amdgcn_mfma_f32_16x16x32_bf16(     \
          av[_m][_k], bv[_n][_k], acc[(mh)*4+_m][(nh)*2+_n], 0, 0, 0);         \
    __builtin_amdgcn_s_setprio(0);                                             \
  } while (0)

#define BAR() __builtin_amdgcn_s_barrier()
#define VM6() asm volatile("s_waitcnt vmcnt(6)" ::: "memory")
#define VM0() asm volatile("s_waitcnt vmcnt(0)" ::: "memory")

#define GEMM8_BODY(NT)                                                         \
  f32x4 acc[8][4];                                                             \
  _Pragma("unroll")                                                            \
  for (int m = 0; m < 8; ++m)                                                  \
    _Pragma("unroll")                                                          \
    for (int n = 0; n < 4; ++n) acc[m][n] = (f32x4)0.0f;                       \
  short8 a[4][2], b0[2][2], b1[2][2];                                          \
  STG(0, 1, 0, 0); STG(0, 1, 1, 0); STG(0, 0, 0, 0); STG(0, 0, 1, 0);          \
  STG(1, 1, 0, 1); STG(1, 1, 1, 1); STG(1, 0, 0, 1);                           \
  VM6(); BAR();                                                                \
  for (int t = 0; t < (NT); ++t) {                                             \
    const bool pf = (t < (NT) - 1);                                            \
    /* ph1 */                                                                  \
    LDA8(a, 0, 0); LDB4(b0, 0, 0);                                             \
    STG(1, 0, 1, 2 * t + 1);                                                   \
    BAR(); MFMA16(0, 0, a, b0); BAR();                                         \
    /* ph2 */                                                                  \
    LDB4(b1, 0, 1);                                                            \
    BAR(); MFMA16(0, 1, a, b1); BAR();                                         \
    /* ph3 */                                                                  \
    LDA8(a, 0, 1);                                                             \
    if (pf) { STG(0, 1, 0, 2 * t + 2); STG(0, 1, 1, 2 * t + 2); }              \
    BAR(); MFMA16(1, 1, a, b1); BAR();                                         \
    /* ph4 */                                                                  \
    if (pf) STG(0, 0, 0, 2 * t + 2);                                           \
    BAR(); MFMA16(1, 0, a, b0);                                                \
    if (pf) VM6(); else VM0();                                                 \
    BAR();                                                                     \
    /* ph5 */                                                                  \
    LDA8(a, 1, 0); LDB4(b0, 1, 0);                                             \
    if (pf) STG(0, 0, 1, 2 * t + 2);                                           \
    BAR(); MFMA16(0, 0, a, b0); BAR();                                         \
    /* ph6 */                                                                  \
    LDB4(b1, 1, 1);                                                            \
    BAR(); MFMA16(0, 1, a, b1); BAR();                                         \
    /* ph7 */                                                                  \
    LDA8(a, 1, 1);                                                             \
    if (pf) { STG(1, 1, 0, 2 * t + 3); STG(1, 1, 1, 2 * t + 3); }              \
    BAR(); MFMA16(1, 1, a, b1); BAR();                                         \
    /* ph8 */                                                                  \
    if (pf) STG(1, 0, 0, 2 * t + 3);                                           \
    BAR(); MFMA16(1, 0, a, b0);                                                \
    if (pf) VM6();                                                             \
    BAR();                                                                     \
  }

// ---- [y|V] = x . [M^T ; Wv^T]^T ; grid (x=row 32, y=col 8) for XCD grouping.
// V-blocks write Vt via LDS bounce: scattered 8B stores -> coalesced dwordx4.
__global__ __launch_bounds__(512, 2) void gemm8_yv(
    const unsigned short* __restrict__ A, const unsigned short* __restrict__ Bt,
    unsigned short* __restrict__ y, unsigned short* __restrict__ vt)
{
  const int row0 = blockIdx.x * 256;
  const int col0 = blockIdx.y * 256;
  const unsigned short* Az = A;
  const unsigned short* Bz = Bt;
  const int lda = 1024, ldb = 1024;

  __shared__ __align__(16) char lds[131072];

  const int tid = threadIdx.x;
  const int wave = tid >> 6, lane = tid & 63;
  const int wr = wave >> 2, wc = wave & 3;
  const int srow = lane >> 3, sgrp = (lane & 7) ^ srow;
  const int kbyte = (lane >> 4) * 16;

  GEMM8_BODY(8)

  if (col0 < 1024) {
    const int orow = row0 + wr * 128 + ((lane >> 4) << 2);
    const int ocol = col0 + wc * 64 + (lane & 15);
    #pragma unroll
    for (int m = 0; m < 8; ++m)
      #pragma unroll
      for (int r = 0; r < 4; ++r) {
        const int rg = orow + m * 16 + r;
        #pragma unroll
        for (int n = 0; n < 4; ++n)
          y[(long long)rg * 1024 + ocol + n * 16] = f2b(acc[m][n][r]);
      }
  } else {
    // transpose tile in LDS: [d 256][t 256] bf16, XOR-swizzled rows (2-way free)
    const int b = row0 >> 11;
    const int t_base = row0 & 2047;
    const int d_base = col0 - 1024;
    const int t_loc0 = wr * 128 + ((lane >> 4) << 2);
    const int d_loc0 = wc * 64 + (lane & 15);
    #pragma unroll
    for (int n = 0; n < 4; ++n) {
      const int d = d_loc0 + n * 16;
      const int sw = (d & 7) << 4;
      #pragma unroll
      for (int m = 0; m < 8; ++m) {
        short4v v;
        v[0] = (short)f2b(acc[m][n][0]);
        v[1] = (short)f2b(acc[m][n][1]);
        v[2] = (short)f2b(acc[m][n][2]);
        v[3] = (short)f2b(acc[m][n][3]);
        const int t = t_loc0 + m * 16;
        *(short4v*)(lds + d * 512 + ((t * 2) ^ sw)) = v;
      }
    }
    __syncthreads();
    #pragma unroll
    for (int it = 0; it < 16; ++it) {
      const int dl = it * 16 + (tid >> 5);
      const int tb = (tid & 31) * 16;  // byte offset within 512B t-row
      const uint4 v = *(const uint4*)(lds + dl * 512 + (tb ^ ((dl & 7) << 4)));
      *(uint4*)((char*)(vt + ((long long)(b * 1024 + d_base + dl) * 2048 + t_base)) + tb) = v;
    }
  }
}

// ---- P = exp((y x^T)/32) causal + rowsum atomics (r14 grid orientation) ----
__global__ __launch_bounds__(512, 2) void gemm8_p(
    const unsigned short* __restrict__ A, const unsigned short* __restrict__ Bt,
    unsigned short* __restrict__ outp, float* __restrict__ sums)
{
  const int z = blockIdx.z;
  const int row0 = blockIdx.y * 256;
  const int col0 = blockIdx.x * 256;
  if (col0 > row0 + 255) return;

  const unsigned short* Az = A + (long long)z * (2048 * 1024);
  const unsigned short* Bz = Bt + (long long)z * (2048 * 1024);
  const int lda = 1024, ldb = 1024;

  __shared__ __align__(16) char lds[131072];

  const int tid = threadIdx.x;
  const int wave = tid >> 6, lane = tid & 63;
  const int wr = wave >> 2, wc = wave & 3;
  const int srow = lane >> 3, sgrp = (lane & 7) ^ srow;
  const int kbyte = (lane >> 4) * 16;

  GEMM8_BODY(8)

  const int orow = row0 + wr * 128 + ((lane >> 4) << 2);
  const int ocol = col0 + wc * 64 + (lane & 15);
  unsigned short* out = outp + (long long)z * (2048 * 2048);
  #pragma unroll
  for (int m = 0; m < 8; ++m)
    #pragma unroll
    for (int r = 0; r < 4; ++r) {
      const int rg = orow + m * 16 + r;
      float rs = 0.f;
      #pragma unroll
      for (int n = 0; n < 4; ++n) {
        const int cg = ocol + n * 16;
        float p = (cg > rg) ? 0.0f : __expf(acc[m][n][r] * 0.03125f);
        rs += p;
        out[(long long)rg * 2048 + cg] = f2b(p);
      }
      #pragma unroll
      for (int off = 1; off < 16; off <<= 1) rs += __shfl_xor(rs, off);
      if ((lane & 15) == 0) atomicAdd(&sums[(long long)z * 2048 + rg], rs);
    }
}

// ==================== 128x64 2-phase PV, pair-fused uniform blocks ====================
__global__ __launch_bounds__(256) void gemm_pv(
    const unsigned short* __restrict__ P, const unsigned short* __restrict__ Vt,
    float* __restrict__ out, const float* __restrict__ sums)
{
  const int z = blockIdx.z;
  const int sx = blockIdx.x;
  const int col0 = blockIdx.y * 64;

  const unsigned short* Pz = P + (long long)z * (2048 * 2048);
  const unsigned short* Bz = Vt + (long long)z * (1024 * 2048);

  __shared__ __align__(16) char lds[24576];   // A [128][64] 16KB, B [64][64] 8KB

  const int tid = threadIdx.x;
  const int wave = tid >> 6;
  const int lane = tid & 63;
  const int wr = wave >> 1, wc = wave & 1;
  const int l15 = lane & 15, lk = lane >> 4;

  const int srow = lane >> 3;
  const int sgrp = (lane & 7) ^ srow;

  const int rA = wr * 64 + l15;
  const int cB = wc * 32 + l15;
  const int kb = lk * 16;
  const int xorA = (rA & 7) << 4;
  const int xorB = (cB & 7) << 4;

  const float* sz = sums + (long long)z * 2048;
  float* oz = out + (long long)z * (2048 * 1024);

  for (int half = 0; half < 2; ++half) {
    const int by = (half == 0) ? (15 - sx) : sx;
    const int row0 = by * 128;
    const int nkt = (row0 + 128) >> 6;

    f32x4 acc[4][2];
    #pragma unroll
    for (int m = 0; m < 4; ++m) { acc[m][0] = (f32x4)0.0f; acc[m][1] = (f32x4)0.0f; }

    for (int kt = 0; kt < nkt; ++kt) {
      const int kc = kt * 64;
      #pragma unroll
      for (int i = 0; i < 4; ++i) {
        const int ci = wave * 4 + i;
        gload16(Pz + (long long)(row0 + ci * 8 + srow) * 2048 + kc + sgrp * 8,
                lds + ci * 1024);
      }
      #pragma unroll
      for (int i = 0; i < 2; ++i) {
        const int ci = wave * 2 + i;
        gload16(Bz + (long long)(col0 + ci * 8 + srow) * 2048 + kc + sgrp * 8,
                lds + 16384 + ci * 1024);
      }
      __syncthreads();
      #pragma unroll
      for (int ks = 0; ks < 2; ++ks) {
        short8 af[4], bfr[2];
        #pragma unroll
        for (int m = 0; m < 4; ++m)
          af[m] = *(const short8*)(lds + (rA + m * 16) * 128 + ((ks * 64 + kb) ^ xorA));
        #pragma unroll
        for (int n = 0; n < 2; ++n)
          bfr[n] = *(const short8*)(lds + 16384 + (cB + n * 16) * 128 + ((ks * 64 + kb) ^ xorB));
        #pragma unroll
        for (int m = 0; m < 4; ++m)
          #pragma unroll
          for (int n = 0; n < 2; ++n)
            acc[m][n] = __builtin_amdgcn_mfma_f32_16x16x32_bf16(af[m], bfr[n], acc[m][n], 0, 0, 0);
      }
      __syncthreads();
    }

    const int orow = row0 + wr * 64 + lk * 4;
    const int ocol = col0 + wc * 32 + l15;
    #pragma unroll
    for (int m = 0; m < 4; ++m)
      #pragma unroll
      for (int r = 0; r < 4; ++r) {
        const int rg = orow + m * 16 + r;
        const float iv = 1.0f / sz[rg];
        #pragma unroll
        for (int n = 0; n < 2; ++n)
          oz[(long long)rg * 1024 + ocol + n * 16] = acc[m][n][r] * iv;
      }
  }
}

extern "C" void kernel_launch(void* const* d_in, const int* in_sizes, int n_in,
                              void* d_out, int out_size, void* d_ws, size_t ws_size,
                              hipStream_t stream) {
  (void)in_sizes; (void)n_in; (void)out_size; (void)ws_size;
  const float* x  = (const float*)d_in[0];
  const float* Wq = (const float*)d_in[1];
  const float* Wk = (const float*)d_in[2];
  const float* Wv = (const float*)d_in[3];
  float* out = (float*)d_out;

  char* ws = (char*)d_ws;
  unsigned short* xb  = (unsigned short*)(ws);               // 8192x1024 bf16
  unsigned short* Wt2 = (unsigned short*)(ws + 16777216);    // [2048][1024]: M^T ; Wv^T
  unsigned short* y   = (unsigned short*)(ws + 20971520);    // 8192x1024 bf16
  unsigned short* Vt  = (unsigned short*)(ws + 37748736);    // 4x1024x2048 bf16
  unsigned short* P   = (unsigned short*)(ws + 54525952);    // 4x2048x2048 bf16
  float*          sums = (float*)(ws + 88080384);            // 4x2048 fp32

  // 1. prep: M^T GEMM first (prefetched), Wv transpose, cvt x, zero sums
  prep<<<9504, 256, 0, stream>>>(x, Wq, Wk, Wv, xb, Wt2, sums);

  // 2. [y | V] = x . [M^T ; Wv^T]^T  (256 gemm8 blocks; Vt via LDS-bounce)
  gemm8_yv<<<dim3(32, 8), 512, 0, stream>>>(xb, Wt2, y, Vt);

  // 3. P = exp((y x^T)/32) causal + rowsums  (r14 grid orientation)
  gemm8_p<<<dim3(8, 8, 4), 512, 0, stream>>>(y, xb, P, sums);

  // 4. context = (P Vt^T)/rowsum  (pair-fused 128x64 2-phase, 512 uniform blocks)
  gemm_pv<<<dim3(8, 16, 4), 256, 0, stream>>>(P, Vt, out, sums);
}

// Round 17
// 128.078 us; speedup vs baseline: 1.2001x; 1.0106x over previous
//
#include <hip/hip_runtime.h>
#include <hip/hip_bf16.h>
#include <stdint.h>

typedef short short8 __attribute__((ext_vector_type(8)));
typedef short short4v __attribute__((ext_vector_type(4)));
typedef float f32x4 __attribute__((ext_vector_type(4)));

__device__ __forceinline__ void gload16(const void* g, void* l) {
  __builtin_amdgcn_global_load_lds((const __attribute__((address_space(1))) void*)g,
                                   (__attribute__((address_space(3))) void*)l, 16, 0, 0);
}

__device__ __forceinline__ unsigned short f2b(float f) {
  unsigned int x = __float_as_uint(f);
  x += 0x7fffu + ((x >> 16) & 1u);
  return (unsigned short)(x >> 16);
}

// ==================== prep ====================
// [0,256) M^T=Wk.Wq^T (long pole, FIRST, prefetched) | [256,1280) Wv->Wt2_V^T |
// [1280,9472) cvt x->xb | [9472,9504) sums=0
__global__ __launch_bounds__(256) void prep(
    const float* __restrict__ x, const float* __restrict__ Wq,
    const float* __restrict__ Wk, const float* __restrict__ Wv,
    unsigned short* __restrict__ xb, unsigned short* __restrict__ Wt2,
    float* __restrict__ sums)
{
  __shared__ __align__(16) char smem[16384];
  const int bid = blockIdx.x;
  const int tid = threadIdx.x;
  if (bid < 256) {
    const int t = bid;
    const int bx = t & 15, by = t >> 4;
    const int row0 = by * 64, col0 = bx * 64;
    const int wave = tid >> 6, lane = tid & 63;
    const int wr = wave >> 1, wc = wave & 1;
    const int l15 = lane & 15, lk = lane >> 4;
    const int sr = lane >> 3, sg = lane & 7;
    char* lA = smem;
    char* lB = smem + 8192;
    const int rA = wr * 32 + l15, cB = wc * 32 + l15;
    const int xorA = (rA & 7) << 4, xorB = (cB & 7) << 4;
    const int kb = lk * 16;
    const int rr0 = (wave * 2 + 0) * 8 + sr;
    const int rr1 = (wave * 2 + 1) * 8 + sr;
    f32x4 acc[2][2];
    #pragma unroll
    for (int m = 0; m < 2; ++m)
      #pragma unroll
      for (int n = 0; n < 2; ++n) acc[m][n] = (f32x4)0.0f;

    float4 rA0[2][2], rA1[2][2], rB0[2][2], rB1[2][2];   // [buf][j]
#define MISSUE(buf, kt) do {                                                  \
      _Pragma("unroll")                                                       \
      for (int _j = 0; _j < 2; ++_j) {                                        \
        const int _r = _j ? rr1 : rr0;                                        \
        const float* _pa = Wk + (long long)(row0 + _r) * 1024 + (kt) * 64 + sg * 8; \
        const float* _pb = Wq + (long long)(col0 + _r) * 1024 + (kt) * 64 + sg * 8; \
        rA0[buf][_j] = *(const float4*)_pa;  rA1[buf][_j] = *(const float4*)(_pa + 4); \
        rB0[buf][_j] = *(const float4*)_pb;  rB1[buf][_j] = *(const float4*)(_pb + 4); \
      } } while (0)

    MISSUE(0, 0);
    #pragma unroll
    for (int kt = 0; kt < 16; ++kt) {
      const int cb = kt & 1;
      if (kt < 15) MISSUE(cb ^ 1, kt + 1);
      __syncthreads();
      #pragma unroll
      for (int j = 0; j < 2; ++j) {
        const int r = j ? rr1 : rr0;
        short8 va, vb;
        va[0] = (short)f2b(rA0[cb][j].x); va[1] = (short)f2b(rA0[cb][j].y);
        va[2] = (short)f2b(rA0[cb][j].z); va[3] = (short)f2b(rA0[cb][j].w);
        va[4] = (short)f2b(rA1[cb][j].x); va[5] = (short)f2b(rA1[cb][j].y);
        va[6] = (short)f2b(rA1[cb][j].z); va[7] = (short)f2b(rA1[cb][j].w);
        vb[0] = (short)f2b(rB0[cb][j].x); vb[1] = (short)f2b(rB0[cb][j].y);
        vb[2] = (short)f2b(rB0[cb][j].z); vb[3] = (short)f2b(rB0[cb][j].w);
        vb[4] = (short)f2b(rB1[cb][j].x); vb[5] = (short)f2b(rB1[cb][j].y);
        vb[6] = (short)f2b(rB1[cb][j].z); vb[7] = (short)f2b(rB1[cb][j].w);
        const int off = r * 128 + ((sg * 16) ^ ((r & 7) << 4));
        *(short8*)(lA + off) = va;
        *(short8*)(lB + off) = vb;
      }
      __syncthreads();
      #pragma unroll
      for (int ks = 0; ks < 2; ++ks) {
        short8 af[2], bf[2];
        #pragma unroll
        for (int m = 0; m < 2; ++m)
          af[m] = *(const short8*)(lA + (rA + m * 16) * 128 + ((ks * 64 + kb) ^ xorA));
        #pragma unroll
        for (int n = 0; n < 2; ++n)
          bf[n] = *(const short8*)(lB + (cB + n * 16) * 128 + ((ks * 64 + kb) ^ xorB));
        #pragma unroll
        for (int m = 0; m < 2; ++m)
          #pragma unroll
          for (int n = 0; n < 2; ++n)
            acc[m][n] = __builtin_amdgcn_mfma_f32_16x16x32_bf16(af[m], bf[n], acc[m][n], 0, 0, 0);
      }
    }
    const int orow = row0 + wr * 32 + lk * 4;
    const int ocol = col0 + wc * 32 + l15;
    #pragma unroll
    for (int m = 0; m < 2; ++m)
      #pragma unroll
      for (int r = 0; r < 4; ++r)
        #pragma unroll
        for (int n = 0; n < 2; ++n)
          Wt2[(long long)(orow + m * 16 + r) * 1024 + ocol + n * 16] = f2b(acc[m][n][r]);
  } else if (bid < 1280) {
    float (*tb)[33] = (float(*)[33])smem;
    const int t = bid - 256;
    const int bx = t & 31, by = t >> 5;
    const int tx = tid & 31, ty = tid >> 5;
    const int xcol = bx * 32 + tx, y0 = by * 32;
    #pragma unroll
    for (int i = 0; i < 4; ++i)
      tb[ty + i * 8][tx] = Wv[(long long)(y0 + ty + i * 8) * 1024 + xcol];
    __syncthreads();
    unsigned short* O = Wt2 + 1024 * 1024;
    const int xo = by * 32 + tx, yo0 = bx * 32;
    #pragma unroll
    for (int i = 0; i < 4; ++i)
      O[(long long)(yo0 + ty + i * 8) * 1024 + xo] = f2b(tb[tx][ty + i * 8]);
  } else if (bid < 9472) {
    const int i = (bid - 1280) * 256 + tid;
    const float4 f = ((const float4*)x)[i];
    union { unsigned short u[4]; uint2 v; } o;
    o.u[0] = f2b(f.x); o.u[1] = f2b(f.y); o.u[2] = f2b(f.z); o.u[3] = f2b(f.w);
    ((uint2*)xb)[i] = o.v;
  } else {
    const int i = (bid - 9472) * 256 + tid;
    sums[i] = 0.f;
  }
}

// ==================== 256x256 8-phase GEMM machinery (vmcnt(6)) ====================
#define STG(buf, isB, half, kt) do {                                           \
    const unsigned short* _s = (isB) ? Bz : Az;                                \
    const int _ld = (isB) ? ldb : lda;                                         \
    const int _b0 = (isB) ? col0 : row0;                                       \
    char* _d = lds + (buf) * 65536 + (isB) * 32768 + (half) * 16384;           \
    _Pragma("unroll")                                                          \
    for (int _i = 0; _i < 2; ++_i) {                                           \
      const int _c = wave * 2 + _i;                                            \
      const int _row = (half) * 128 + _c * 8 + srow;                           \
      gload16(_s + (long long)(_b0 + _row) * _ld + (kt) * 64 + sgrp * 8,       \
              _d + _c * 1024);                                                 \
    } } while (0)

#define LDA8(dst, buf, mh) do {                                                \
    _Pragma("unroll")                                                          \
    for (int _m = 0; _m < 4; ++_m) {                                           \
      const int _r = wr * 128 + ((mh) * 4 + _m) * 16 + (lane & 15);            \
      const char* _p = lds + (buf) * 65536 + _r * 128;                         \
      const int _x = (_r & 7) << 4;                                            \
      dst[_m][0] = *(const short8*)(_p + ((kbyte) ^ _x));                      \
      dst[_m][1] = *(const short8*)(_p + ((64 + kbyte) ^ _x));                 \
    } } while (0)

#define LDB4(dst, buf, nh) do {                                                \
    _Pragma("unroll")                                                          \
    for (int _n = 0; _n < 2; ++_n) {                                           \
      const int _r = wc * 64 + ((nh) * 2 + _n) * 16 + (lane & 15);             \
      const char* _p = lds + (buf) * 65536 + 32768 + _r * 128;                 \
      const int _x = (_r & 7) << 4;                                            \
      dst[_n][0] = *(const short8*)(_p + ((kbyte) ^ _x));                      \
      dst[_n][1] = *(const short8*)(_p + ((64 + kbyte) ^ _x));                 \
    } } while (0)

#define MFMA16(mh, nh, av, bv) do {                                            \
    __builtin_amdgcn_s_setprio(1);                                             \
    _Pragma("unroll") for (int _n = 0; _n < 2; ++_n)                           \
    _Pragma("unroll") for (int _m = 0; _m < 4; ++_m)                           \
    _Pragma("unroll") for (int _k = 0; _k < 2; ++_k)                           \
      acc[(mh)*4+_m][(nh)*2+_n] = __builtin_amdgcn_mfma_f32_16x16x32_bf16(     \
          av[_m][_k], bv[_n][_k], acc[(mh)*4+_m][(nh)*2+_n], 0, 0, 0);         \
    __builtin_amdgcn_s_setprio(0);                                             \
  } while (0)

#define BAR() __builtin_amdgcn_s_barrier()
#define VM6() asm volatile("s_waitcnt vmcnt(6)" ::: "memory")
#define VM0() asm volatile("s_waitcnt vmcnt(0)" ::: "memory")

#define GEMM8_BODY(NT)                                                         \
  f32x4 acc[8][4];                                                             \
  _Pragma("unroll")                                                            \
  for (int m = 0; m < 8; ++m)                                                  \
    _Pragma("unroll")                                                          \
    for (int n = 0; n < 4; ++n) acc[m][n] = (f32x4)0.0f;                       \
  short8 a[4][2], b0[2][2], b1[2][2];                                          \
  STG(0, 1, 0, 0); STG(0, 1, 1, 0); STG(0, 0, 0, 0); STG(0, 0, 1, 0);          \
  STG(1, 1, 0, 1); STG(1, 1, 1, 1); STG(1, 0, 0, 1);                           \
  VM6(); BAR();                                                                \
  for (int t = 0; t < (NT); ++t) {                                             \
    const bool pf = (t < (NT) - 1);                                            \
    /* ph1 */                                                                  \
    LDA8(a, 0, 0); LDB4(b0, 0, 0);                                             \
    STG(1, 0, 1, 2 * t + 1);                                                   \
    BAR(); MFMA16(0, 0, a, b0); BAR();                                         \
    /* ph2 */                                                                  \
    LDB4(b1, 0, 1);                                                            \
    BAR(); MFMA16(0, 1, a, b1); BAR();                                         \
    /* ph3 */                                                                  \
    LDA8(a, 0, 1);                                                             \
    if (pf) { STG(0, 1, 0, 2 * t + 2); STG(0, 1, 1, 2 * t + 2); }              \
    BAR(); MFMA16(1, 1, a, b1); BAR();                                         \
    /* ph4 */                                                                  \
    if (pf) STG(0, 0, 0, 2 * t + 2);                                           \
    BAR(); MFMA16(1, 0, a, b0);                                                \
    if (pf) VM6(); else VM0();                                                 \
    BAR();                                                                     \
    /* ph5 */                                                                  \
    LDA8(a, 1, 0); LDB4(b0, 1, 0);                                             \
    if (pf) STG(0, 0, 1, 2 * t + 2);                                           \
    BAR(); MFMA16(0, 0, a, b0); BAR();                                         \
    /* ph6 */                                                                  \
    LDB4(b1, 1, 1);                                                            \
    BAR(); MFMA16(0, 1, a, b1); BAR();                                         \
    /* ph7 */                                                                  \
    LDA8(a, 1, 1);                                                             \
    if (pf) { STG(1, 1, 0, 2 * t + 3); STG(1, 1, 1, 2 * t + 3); }              \
    BAR(); MFMA16(1, 1, a, b1); BAR();                                         \
    /* ph8 */                                                                  \
    if (pf) STG(1, 0, 0, 2 * t + 3);                                           \
    BAR(); MFMA16(1, 0, a, b0);                                                \
    if (pf) VM6();                                                             \
    BAR();                                                                     \
  }

// ---- [y|V] = x . [M^T ; Wv^T]^T ; grid (x=row 32, y=col 8) for XCD grouping.
// V-blocks write Vt via LDS bounce: scattered 8B stores -> coalesced dwordx4.
__global__ __launch_bounds__(512, 2) void gemm8_yv(
    const unsigned short* __restrict__ A, const unsigned short* __restrict__ Bt,
    unsigned short* __restrict__ y, unsigned short* __restrict__ vt)
{
  const int row0 = blockIdx.x * 256;
  const int col0 = blockIdx.y * 256;
  const unsigned short* Az = A;
  const unsigned short* Bz = Bt;
  const int lda = 1024, ldb = 1024;

  __shared__ __align__(16) char lds[131072];

  const int tid = threadIdx.x;
  const int wave = tid >> 6, lane = tid & 63;
  const int wr = wave >> 2, wc = wave & 3;
  const int srow = lane >> 3, sgrp = (lane & 7) ^ srow;
  const int kbyte = (lane >> 4) * 16;

  GEMM8_BODY(8)

  if (col0 < 1024) {
    const int orow = row0 + wr * 128 + ((lane >> 4) << 2);
    const int ocol = col0 + wc * 64 + (lane & 15);
    #pragma unroll
    for (int m = 0; m < 8; ++m)
      #pragma unroll
      for (int r = 0; r < 4; ++r) {
        const int rg = orow + m * 16 + r;
        #pragma unroll
        for (int n = 0; n < 4; ++n)
          y[(long long)rg * 1024 + ocol + n * 16] = f2b(acc[m][n][r]);
      }
  } else {
    // transpose tile in LDS: [d 256][t 256] bf16, XOR-swizzled rows (2-way free)
    const int b = row0 >> 11;
    const int t_base = row0 & 2047;
    const int d_base = col0 - 1024;
    const int t_loc0 = wr * 128 + ((lane >> 4) << 2);
    const int d_loc0 = wc * 64 + (lane & 15);
    #pragma unroll
    for (int n = 0; n < 4; ++n) {
      const int d = d_loc0 + n * 16;
      const int sw = (d & 7) << 4;
      #pragma unroll
      for (int m = 0; m < 8; ++m) {
        short4v v;
        v[0] = (short)f2b(acc[m][n][0]);
        v[1] = (short)f2b(acc[m][n][1]);
        v[2] = (short)f2b(acc[m][n][2]);
        v[3] = (short)f2b(acc[m][n][3]);
        const int t = t_loc0 + m * 16;
        *(short4v*)(lds + d * 512 + ((t * 2) ^ sw)) = v;
      }
    }
    __syncthreads();
    #pragma unroll
    for (int it = 0; it < 16; ++it) {
      const int dl = it * 16 + (tid >> 5);
      const int tb = (tid & 31) * 16;  // byte offset within 512B t-row
      const uint4 v = *(const uint4*)(lds + dl * 512 + (tb ^ ((dl & 7) << 4)));
      *(uint4*)((char*)(vt + ((long long)(b * 1024 + d_base + dl) * 2048 + t_base)) + tb) = v;
    }
  }
}

// ---- P = exp((y x^T)/32) causal + rowsum atomics (r14 grid orientation) ----
__global__ __launch_bounds__(512, 2) void gemm8_p(
    const unsigned short* __restrict__ A, const unsigned short* __restrict__ Bt,
    unsigned short* __restrict__ outp, float* __restrict__ sums)
{
  const int z = blockIdx.z;
  const int row0 = blockIdx.y * 256;
  const int col0 = blockIdx.x * 256;
  if (col0 > row0 + 255) return;

  const unsigned short* Az = A + (long long)z * (2048 * 1024);
  const unsigned short* Bz = Bt + (long long)z * (2048 * 1024);
  const int lda = 1024, ldb = 1024;

  __shared__ __align__(16) char lds[131072];

  const int tid = threadIdx.x;
  const int wave = tid >> 6, lane = tid & 63;
  const int wr = wave >> 2, wc = wave & 3;
  const int srow = lane >> 3, sgrp = (lane & 7) ^ srow;
  const int kbyte = (lane >> 4) * 16;

  GEMM8_BODY(8)

  const int orow = row0 + wr * 128 + ((lane >> 4) << 2);
  const int ocol = col0 + wc * 64 + (lane & 15);
  unsigned short* out = outp + (long long)z * (2048 * 2048);
  #pragma unroll
  for (int m = 0; m < 8; ++m)
    #pragma unroll
    for (int r = 0; r < 4; ++r) {
      const int rg = orow + m * 16 + r;
      float rs = 0.f;
      #pragma unroll
      for (int n = 0; n < 4; ++n) {
        const int cg = ocol + n * 16;
        float p = (cg > rg) ? 0.0f : __expf(acc[m][n][r] * 0.03125f);
        rs += p;
        out[(long long)rg * 2048 + cg] = f2b(p);
      }
      #pragma unroll
      for (int off = 1; off < 16; off <<= 1) rs += __shfl_xor(rs, off);
      if ((lane & 15) == 0) atomicAdd(&sums[(long long)z * 2048 + rg], rs);
    }
}

// ==================== 128x64 2-phase PV, pair-fused, BK=128 unroll ====================
// grid (x=pair 8, y=col 16, z=batch). Two stripes per block (by=15-sx then sx),
// uniform work. BK=128: stage TWO 64-col K-tiles per barrier pair (12 gload16),
// then 64 MFMA/wave -> halves barrier drains vs BK=64. LDS 48KB (A0|A1|B0|B1),
// grid-limited 2 blocks/CU unchanged. Stripe K-tile counts are even -> no tail.
__global__ __launch_bounds__(256) void gemm_pv(
    const unsigned short* __restrict__ P, const unsigned short* __restrict__ Vt,
    float* __restrict__ out, const float* __restrict__ sums)
{
  const int z = blockIdx.z;
  const int sx = blockIdx.x;
  const int col0 = blockIdx.y * 64;

  const unsigned short* Pz = P + (long long)z * (2048 * 2048);
  const unsigned short* Bz = Vt + (long long)z * (1024 * 2048);

  __shared__ __align__(16) char lds[49152];  // A0 16K | A1 16K | B0 8K | B1 8K

  const int tid = threadIdx.x;
  const int wave = tid >> 6;
  const int lane = tid & 63;
  const int wr = wave >> 1, wc = wave & 1;
  const int l15 = lane & 15, lk = lane >> 4;

  const int srow = lane >> 3;
  const int sgrp = (lane & 7) ^ srow;

  const int rA = wr * 64 + l15;
  const int cB = wc * 32 + l15;
  const int kb = lk * 16;
  const int xorA = (rA & 7) << 4;
  const int xorB = (cB & 7) << 4;

  const float* sz = sums + (long long)z * 2048;
  float* oz = out + (long long)z * (2048 * 1024);

  for (int half = 0; half < 2; ++half) {
    const int by = (half == 0) ? (15 - sx) : sx;
    const int row0 = by * 128;
    const int nk2 = (row0 + 128) >> 7;   // BK=128 steps; always exact

    f32x4 acc[4][2];
    #pragma unroll
    for (int m = 0; m < 4; ++m) { acc[m][0] = (f32x4)0.0f; acc[m][1] = (f32x4)0.0f; }

    for (int kt2 = 0; kt2 < nk2; ++kt2) {
      const int kc = kt2 * 128;
      #pragma unroll
      for (int i = 0; i < 4; ++i) {
        const int ci = wave * 4 + i;
        const unsigned short* prow = Pz + (long long)(row0 + ci * 8 + srow) * 2048 + sgrp * 8;
        gload16(prow + kc,      lds + ci * 1024);            // A tile0
        gload16(prow + kc + 64, lds + 16384 + ci * 1024);    // A tile1
      }
      #pragma unroll
      for (int i = 0; i < 2; ++i) {
        const int ci = wave * 2 + i;
        const unsigned short* vrow = Bz + (long long)(col0 + ci * 8 + srow) * 2048 + sgrp * 8;
        gload16(vrow + kc,      lds + 32768 + ci * 1024);    // B tile0
        gload16(vrow + kc + 64, lds + 40960 + ci * 1024);    // B tile1
      }
      __syncthreads();
      #pragma unroll
      for (int tl = 0; tl < 2; ++tl) {
        const char* la = lds + tl * 16384;
        const char* lb = lds + 32768 + tl * 8192;
        #pragma unroll
        for (int ks = 0; ks < 2; ++ks) {
          short8 af[4], bfr[2];
          #pragma unroll
          for (int m = 0; m < 4; ++m)
            af[m] = *(const short8*)(la + (rA + m * 16) * 128 + ((ks * 64 + kb) ^ xorA));
          #pragma unroll
          for (int n = 0; n < 2; ++n)
            bfr[n] = *(const short8*)(lb + (cB + n * 16) * 128 + ((ks * 64 + kb) ^ xorB));
          #pragma unroll
          for (int m = 0; m < 4; ++m)
            #pragma unroll
            for (int n = 0; n < 2; ++n)
              acc[m][n] = __builtin_amdgcn_mfma_f32_16x16x32_bf16(af[m], bfr[n], acc[m][n], 0, 0, 0);
        }
      }
      __syncthreads();
    }

    const int orow = row0 + wr * 64 + lk * 4;
    const int ocol = col0 + wc * 32 + l15;
    #pragma unroll
    for (int m = 0; m < 4; ++m)
      #pragma unroll
      for (int r = 0; r < 4; ++r) {
        const int rg = orow + m * 16 + r;
        const float iv = 1.0f / sz[rg];
        #pragma unroll
        for (int n = 0; n < 2; ++n)
          oz[(long long)rg * 1024 + ocol + n * 16] = acc[m][n][r] * iv;
      }
  }
}

extern "C" void kernel_launch(void* const* d_in, const int* in_sizes, int n_in,
                              void* d_out, int out_size, void* d_ws, size_t ws_size,
                              hipStream_t stream) {
  (void)in_sizes; (void)n_in; (void)out_size; (void)ws_size;
  const float* x  = (const float*)d_in[0];
  const float* Wq = (const float*)d_in[1];
  const float* Wk = (const float*)d_in[2];
  const float* Wv = (const float*)d_in[3];
  float* out = (float*)d_out;

  char* ws = (char*)d_ws;
  unsigned short* xb  = (unsigned short*)(ws);               // 8192x1024 bf16
  unsigned short* Wt2 = (unsigned short*)(ws + 16777216);    // [2048][1024]: M^T ; Wv^T
  unsigned short* y   = (unsigned short*)(ws + 20971520);    // 8192x1024 bf16
  unsigned short* Vt  = (unsigned short*)(ws + 37748736);    // 4x1024x2048 bf16
  unsigned short* P   = (unsigned short*)(ws + 54525952);    // 4x2048x2048 bf16
  float*          sums = (float*)(ws + 88080384);            // 4x2048 fp32

  // 1. prep: M^T GEMM first (prefetched), Wv transpose, cvt x, zero sums
  prep<<<9504, 256, 0, stream>>>(x, Wq, Wk, Wv, xb, Wt2, sums);

  // 2. [y | V] = x . [M^T ; Wv^T]^T  (256 gemm8 blocks; Vt via LDS-bounce)
  gemm8_yv<<<dim3(32, 8), 512, 0, stream>>>(xb, Wt2, y, Vt);

  // 3. P = exp((y x^T)/32) causal + rowsums
  gemm8_p<<<dim3(8, 8, 4), 512, 0, stream>>>(y, xb, P, sums);

  // 4. context = (P Vt^T)/rowsum  (pair-fused 128x64, BK=128, 512 uniform blocks)
  gemm_pv<<<dim3(8, 16, 4), 256, 0, stream>>>(P, Vt, out, sums);
}